// Round 1
// baseline (446.703 us; speedup 1.0000x reference)
//
#include <hip/hip_runtime.h>
#include <hip/hip_bf16.h>

// ---------------------------------------------------------------------------
// GCN classifier: emb-gather -> GCNConv(relu) -> GCNConv(relu) -> mean-pool ->
// linear.  All f32.  CSR built on-device each call (deterministic up to float
// sum order; threshold 2.4e-3 >> 1e-6 reorder noise).
// ---------------------------------------------------------------------------

__global__ void hist_kernel(const int* __restrict__ dst, int* __restrict__ cnt, int E) {
    int i = blockIdx.x * blockDim.x + threadIdx.x;
    if (i < E) atomicAdd(&cnt[dst[i]], 1);
}

__global__ void dis_kernel(const int* __restrict__ cnt, float* __restrict__ dis, int n) {
    int i = blockIdx.x * blockDim.x + threadIdx.x;
    if (i < n) dis[i] = rsqrtf((float)cnt[i] + 1.0f);   // +1 = self loop
}

// single-block exclusive scan of cnt[0..n) -> rowptr[0..n], rowptr[n] = total
__global__ __launch_bounds__(1024) void scan_kernel(const int* __restrict__ cnt,
                                                    int* __restrict__ rowptr, int n) {
    const int T = 1024;
    int t = threadIdx.x;
    int chunk = (n + T - 1) / T;
    int lo = t * chunk;
    int hi = lo + chunk; if (hi > n) hi = n;
    int s = 0;
    for (int i = lo; i < hi && lo < n; ++i) s += cnt[i];
    __shared__ int ps[T];
    ps[t] = s;
    __syncthreads();
    for (int off = 1; off < T; off <<= 1) {
        int v = (t >= off) ? ps[t - off] : 0;
        __syncthreads();
        ps[t] += v;
        __syncthreads();
    }
    int run = (t == 0) ? 0 : ps[t - 1];
    for (int i = lo; i < hi && lo < n; ++i) { rowptr[i] = run; run += cnt[i]; }
    if (t == T - 1) rowptr[n] = ps[T - 1];
}

__global__ void scatter_kernel(const int* __restrict__ src, const int* __restrict__ dst,
                               const int* __restrict__ rowptr, int* __restrict__ tmp,
                               int* __restrict__ csr_src, int E) {
    int i = blockIdx.x * blockDim.x + threadIdx.x;
    if (i < E) {
        int d = dst[i];
        int pos = rowptr[d] + atomicAdd(&tmp[d], 1);
        csr_src[pos] = src[i];
    }
}

// ---------------------------------------------------------------------------
// GEMM: Out[n,128] = X[n,128] @ W[128,128]
// If X == nullptr: X row r = (tokens[r] != 0) ? emb[tokens[r]] : 0   (padding_idx=0)
// Block: 256 threads, tile 128 rows x 128 cols, 8x8 register tile per thread.
// K-sliced (64) staging: ws 32KB + xs (pad 68) 34KB = 66KB LDS -> 2 blocks/CU.
// ---------------------------------------------------------------------------
__global__ __launch_bounds__(256) void gemm128(const float* __restrict__ X,
                                               const int* __restrict__ tokens,
                                               const float* __restrict__ emb,
                                               const float* __restrict__ W,
                                               float* __restrict__ Out, int n) {
    __shared__ float ws[64 * 128];
    __shared__ float xs[128 * 68];
    const int tid = threadIdx.x;
    const int tc = tid & 15;          // col group: cols {tc*4..+3} and {64+tc*4..+3}
    const int tr = tid >> 4;          // row group: rows {tr*4..+3} and {64+tr*4..+3}
    const int rowBase = blockIdx.x * 128;

    float acc[8][8];
#pragma unroll
    for (int i = 0; i < 8; ++i)
#pragma unroll
        for (int j = 0; j < 8; ++j) acc[i][j] = 0.0f;

    for (int kk = 0; kk < 128; kk += 64) {
        // ---- stage W k-slice: 64 x 128
#pragma unroll
        for (int t = 0; t < 8; ++t) {
            int flat4 = t * 256 + tid;           // 0..2047 float4s
            int r  = flat4 >> 5;                 // 0..63
            int c4 = (flat4 & 31) * 4;
            *(float4*)&ws[r * 128 + c4] = *(const float4*)&W[(kk + r) * 128 + c4];
        }
        // ---- stage X slice: 128 rows x 64 k (pad stride 68)
#pragma unroll
        for (int t = 0; t < 8; ++t) {
            int flat4 = t * 256 + tid;
            int r  = flat4 >> 4;                 // 0..127
            int k4 = (flat4 & 15) * 4;
            int grow = rowBase + r;
            float4 v; v.x = v.y = v.z = v.w = 0.0f;
            if (grow < n) {
                if (X) {
                    v = *(const float4*)&X[(size_t)grow * 128 + kk + k4];
                } else {
                    int tok = tokens[grow];
                    if (tok != 0) v = *(const float4*)&emb[(size_t)tok * 128 + kk + k4];
                }
            }
            *(float4*)&xs[r * 68 + k4] = v;
        }
        __syncthreads();

#pragma unroll
        for (int kc = 0; kc < 16; ++kc) {
            const int k = kc * 4;
            float4 xv[8];
#pragma unroll
            for (int i = 0; i < 8; ++i) {
                int r = (i < 4) ? (tr * 4 + i) : (64 + tr * 4 + (i - 4));
                xv[i] = *(const float4*)&xs[r * 68 + k];
            }
#pragma unroll
            for (int d = 0; d < 4; ++d) {
                float4 wA = *(const float4*)&ws[(k + d) * 128 + tc * 4];
                float4 wB = *(const float4*)&ws[(k + d) * 128 + 64 + tc * 4];
#pragma unroll
                for (int i = 0; i < 8; ++i) {
                    float xd = (d == 0) ? xv[i].x : (d == 1) ? xv[i].y : (d == 2) ? xv[i].z : xv[i].w;
                    acc[i][0] += xd * wA.x;
                    acc[i][1] += xd * wA.y;
                    acc[i][2] += xd * wA.z;
                    acc[i][3] += xd * wA.w;
                    acc[i][4] += xd * wB.x;
                    acc[i][5] += xd * wB.y;
                    acc[i][6] += xd * wB.z;
                    acc[i][7] += xd * wB.w;
                }
            }
        }
        __syncthreads();
    }

#pragma unroll
    for (int i = 0; i < 8; ++i) {
        int r = rowBase + ((i < 4) ? (tr * 4 + i) : (64 + tr * 4 + (i - 4)));
        if (r < n) {
            float4 oA, oB;
            oA.x = acc[i][0]; oA.y = acc[i][1]; oA.z = acc[i][2]; oA.w = acc[i][3];
            oB.x = acc[i][4]; oB.y = acc[i][5]; oB.z = acc[i][6]; oB.w = acc[i][7];
            *(float4*)&Out[(size_t)r * 128 + tc * 4]      = oA;
            *(float4*)&Out[(size_t)r * 128 + 64 + tc * 4] = oB;
        }
    }
}

// ---------------------------------------------------------------------------
// Aggregation: Out[n] = relu( dis[n] * sum_{e in CSR(n)} H[src_e]*dis[src_e]
//                           + H[n] * dis[n]^2  + bias )
// 32 lanes per node (float4 per lane), 8 nodes per 256-thread block.
// ---------------------------------------------------------------------------
__global__ __launch_bounds__(256) void aggregate_kernel(const float* __restrict__ H,
                                                        const float* __restrict__ dis,
                                                        const int* __restrict__ rowptr,
                                                        const int* __restrict__ csr_src,
                                                        const float* __restrict__ bias,
                                                        float* __restrict__ Out, int n) {
    const int g = threadIdx.x >> 5;
    const int l = threadIdx.x & 31;
    const int node = blockIdx.x * 8 + g;
    if (node >= n) return;

    const float dn = dis[node];
    const float4 hn = *(const float4*)&H[(size_t)node * 128 + l * 4];
    const int e0 = rowptr[node];
    const int e1 = rowptr[node + 1];

    float sx = 0.f, sy = 0.f, sz = 0.f, sw = 0.f;
    for (int e = e0; e < e1; ++e) {
        int s = csr_src[e];
        float w = dis[s];
        float4 hv = *(const float4*)&H[(size_t)s * 128 + l * 4];
        sx += hv.x * w; sy += hv.y * w; sz += hv.z * w; sw += hv.w * w;
    }
    const float self = dn * dn;
    const float4 b = *(const float4*)&bias[l * 4];
    float4 o;
    o.x = fmaxf(sx * dn + hn.x * self + b.x, 0.0f);
    o.y = fmaxf(sy * dn + hn.y * self + b.y, 0.0f);
    o.z = fmaxf(sz * dn + hn.z * self + b.z, 0.0f);
    o.w = fmaxf(sw * dn + hn.w * self + b.w, 0.0f);
    *(float4*)&Out[(size_t)node * 128 + l * 4] = o;
}

// ---------------------------------------------------------------------------
// Mean pool (sorted batch, binary-searched bounds) + 128x10 linear, per graph.
// ---------------------------------------------------------------------------
__global__ __launch_bounds__(128) void pool_kernel(const float* __restrict__ X,
                                                   const int* __restrict__ batch,
                                                   const float* __restrict__ lw,
                                                   const float* __restrict__ lb,
                                                   float* __restrict__ out, int n) {
    const int gph = blockIdx.x;
    // lower_bound(batch, gph) / lower_bound(batch, gph+1)
    int lo = 0, hi = n;
    while (lo < hi) { int mid = (lo + hi) >> 1; if (batch[mid] < gph) lo = mid + 1; else hi = mid; }
    const int s = lo;
    hi = n;
    while (lo < hi) { int mid = (lo + hi) >> 1; if (batch[mid] < gph + 1) lo = mid + 1; else hi = mid; }
    const int e = lo;

    const int t = threadIdx.x;
    float sum = 0.0f;
    for (int i = s; i < e; ++i) sum += X[(size_t)i * 128 + t];
    __shared__ float pl[128];
    pl[t] = sum / fmaxf((float)(e - s), 1.0f);
    __syncthreads();
    if (t < 10) {
        float acc = lb[t];
#pragma unroll 16
        for (int d = 0; d < 128; ++d) acc += pl[d] * lw[d * 10 + t];
        out[gph * 10 + t] = acc;
    }
}

// ---------------------------------------------------------------------------
extern "C" void kernel_launch(void* const* d_in, const int* in_sizes, int n_in,
                              void* d_out, int out_size, void* d_ws, size_t ws_size,
                              hipStream_t stream) {
    const int*   tokens = (const int*)d_in[0];
    const int*   eidx   = (const int*)d_in[1];
    const int*   batch  = (const int*)d_in[2];
    const float* emb    = (const float*)d_in[3];
    const float* w1     = (const float*)d_in[4];
    const float* b1     = (const float*)d_in[5];
    const float* w2     = (const float*)d_in[6];
    const float* b2     = (const float*)d_in[7];
    const float* lw     = (const float*)d_in[8];
    const float* lbv    = (const float*)d_in[9];

    const int N = in_sizes[0];
    const int E = in_sizes[1] / 2;
    const int G = out_size / 10;
    const int* src = eidx;
    const int* dst = eidx + E;

    char* p = (char*)d_ws;
    auto alloc = [&](size_t bytes) { void* r = (void*)p; p += (bytes + 255) & ~(size_t)255; return r; };
    float* dis    = (float*)alloc((size_t)N * 4);
    int*   cnt    = (int*)  alloc((size_t)N * 4);
    int*   rowptr = (int*)  alloc(((size_t)N + 1) * 4);
    int*   tmp    = (int*)  alloc((size_t)N * 4);
    int*   csr    = (int*)  alloc((size_t)E * 4);
    float* A      = (float*)alloc((size_t)N * 128 * 4);
    float* B      = (float*)alloc((size_t)N * 128 * 4);

    hipMemsetAsync(cnt, 0, (size_t)N * 4, stream);
    hipMemsetAsync(tmp, 0, (size_t)N * 4, stream);

    hist_kernel<<<(E + 255) / 256, 256, 0, stream>>>(dst, cnt, E);
    dis_kernel<<<(N + 255) / 256, 256, 0, stream>>>(cnt, dis, N);
    scan_kernel<<<1, 1024, 0, stream>>>(cnt, rowptr, N);
    scatter_kernel<<<(E + 255) / 256, 256, 0, stream>>>(src, dst, rowptr, tmp, csr, E);

    // layer 1: H = emb[tokens] @ w1 ; X2 = relu(agg(H) + b1)
    gemm128<<<(N + 127) / 128, 256, 0, stream>>>(nullptr, tokens, emb, w1, A, N);
    aggregate_kernel<<<(N + 7) / 8, 256, 0, stream>>>(A, dis, rowptr, csr, b1, B, N);

    // layer 2: H2 = X2 @ w2 ; X3 = relu(agg(H2) + b2)
    gemm128<<<(N + 127) / 128, 256, 0, stream>>>(B, nullptr, nullptr, w2, A, N);
    aggregate_kernel<<<(N + 7) / 8, 256, 0, stream>>>(A, dis, rowptr, csr, b2, B, N);

    // mean pool + classifier
    pool_kernel<<<G, 128, 0, stream>>>(B, batch, lw, lbv, (float*)d_out, N);
}

// Round 2
// 361.440 us; speedup vs baseline: 1.2359x; 1.2359x over previous
//
#include <hip/hip_runtime.h>
#include <hip/hip_bf16.h>

// ---------------------------------------------------------------------------
// GCN classifier: emb-gather -> GCNConv(relu) -> GCNConv(relu) -> mean-pool ->
// linear.  All f32.  CSR built on-device each call.
// R1: replaced 90us single-block scan with 3-phase multi-block scan (+ fused
//     rsqrt into phase 1).
// ---------------------------------------------------------------------------

__global__ void hist_kernel(const int* __restrict__ dst, int* __restrict__ cnt, int E) {
    int i = blockIdx.x * blockDim.x + threadIdx.x;
    if (i < E) atomicAdd(&cnt[dst[i]], 1);
}

// ---- 3-phase scan: phase 1 — per-block (1024 elems, 256 thr x int4) local
//      exclusive scan + block sum; also emits dis[] = rsqrt(cnt+1).
__global__ __launch_bounds__(256) void scan1_kernel(const int* __restrict__ cnt,
                                                    int* __restrict__ rowptr,
                                                    int* __restrict__ bsum,
                                                    float* __restrict__ dis, int n) {
    __shared__ int ls[256];
    const int t = threadIdx.x;
    const int base = blockIdx.x * 1024 + t * 4;
    int v0 = 0, v1 = 0, v2 = 0, v3 = 0;
    if (base + 3 < n) {
        int4 q = *(const int4*)&cnt[base];
        v0 = q.x; v1 = q.y; v2 = q.z; v3 = q.w;
    } else {
        if (base + 0 < n) v0 = cnt[base + 0];
        if (base + 1 < n) v1 = cnt[base + 1];
        if (base + 2 < n) v2 = cnt[base + 2];
        if (base + 3 < n) v3 = cnt[base + 3];
    }
    if (base + 0 < n) dis[base + 0] = rsqrtf((float)v0 + 1.0f);
    if (base + 1 < n) dis[base + 1] = rsqrtf((float)v1 + 1.0f);
    if (base + 2 < n) dis[base + 2] = rsqrtf((float)v2 + 1.0f);
    if (base + 3 < n) dis[base + 3] = rsqrtf((float)v3 + 1.0f);

    ls[t] = v0 + v1 + v2 + v3;
    __syncthreads();
    for (int off = 1; off < 256; off <<= 1) {
        int x = (t >= off) ? ls[t - off] : 0;
        __syncthreads();
        ls[t] += x;
        __syncthreads();
    }
    int run = (t == 0) ? 0 : ls[t - 1];
    if (base + 0 < n) { rowptr[base + 0] = run; run += v0; }
    if (base + 1 < n) { rowptr[base + 1] = run; run += v1; }
    if (base + 2 < n) { rowptr[base + 2] = run; run += v2; }
    if (base + 3 < n) { rowptr[base + 3] = run; run += v3; }
    if (t == 255) bsum[blockIdx.x] = ls[255];
}

// phase 2 — serial exclusive scan of B block sums (B ~ 49), bsum[B] = total
__global__ void scan2_kernel(int* __restrict__ bsum, int B) {
    if (threadIdx.x == 0 && blockIdx.x == 0) {
        int run = 0;
        for (int i = 0; i < B; ++i) { int v = bsum[i]; bsum[i] = run; run += v; }
        bsum[B] = run;
    }
}

// phase 3 — add block offsets; write rowptr[n] = total
__global__ __launch_bounds__(256) void scan3_kernel(const int* __restrict__ bsum,
                                                    int* __restrict__ rowptr, int n, int B) {
    int i = blockIdx.x * blockDim.x + threadIdx.x;
    if (i < n) rowptr[i] += bsum[i >> 10];
    if (i == 0) rowptr[n] = bsum[B];
}

__global__ void scatter_kernel(const int* __restrict__ src, const int* __restrict__ dst,
                               const int* __restrict__ rowptr, int* __restrict__ tmp,
                               int* __restrict__ csr_src, int E) {
    int i = blockIdx.x * blockDim.x + threadIdx.x;
    if (i < E) {
        int d = dst[i];
        int pos = rowptr[d] + atomicAdd(&tmp[d], 1);
        csr_src[pos] = src[i];
    }
}

// ---------------------------------------------------------------------------
// GEMM: Out[n,128] = X[n,128] @ W[128,128]
// If X == nullptr: X row r = (tokens[r] != 0) ? emb[tokens[r]] : 0
// ---------------------------------------------------------------------------
__global__ __launch_bounds__(256) void gemm128(const float* __restrict__ X,
                                               const int* __restrict__ tokens,
                                               const float* __restrict__ emb,
                                               const float* __restrict__ W,
                                               float* __restrict__ Out, int n) {
    __shared__ float ws[64 * 128];
    __shared__ float xs[128 * 68];
    const int tid = threadIdx.x;
    const int tc = tid & 15;
    const int tr = tid >> 4;
    const int rowBase = blockIdx.x * 128;

    float acc[8][8];
#pragma unroll
    for (int i = 0; i < 8; ++i)
#pragma unroll
        for (int j = 0; j < 8; ++j) acc[i][j] = 0.0f;

    for (int kk = 0; kk < 128; kk += 64) {
#pragma unroll
        for (int t = 0; t < 8; ++t) {
            int flat4 = t * 256 + tid;
            int r  = flat4 >> 5;
            int c4 = (flat4 & 31) * 4;
            *(float4*)&ws[r * 128 + c4] = *(const float4*)&W[(kk + r) * 128 + c4];
        }
#pragma unroll
        for (int t = 0; t < 8; ++t) {
            int flat4 = t * 256 + tid;
            int r  = flat4 >> 4;
            int k4 = (flat4 & 15) * 4;
            int grow = rowBase + r;
            float4 v; v.x = v.y = v.z = v.w = 0.0f;
            if (grow < n) {
                if (X) {
                    v = *(const float4*)&X[(size_t)grow * 128 + kk + k4];
                } else {
                    int tok = tokens[grow];
                    if (tok != 0) v = *(const float4*)&emb[(size_t)tok * 128 + kk + k4];
                }
            }
            *(float4*)&xs[r * 68 + k4] = v;
        }
        __syncthreads();

#pragma unroll
        for (int kc = 0; kc < 16; ++kc) {
            const int k = kc * 4;
            float4 xv[8];
#pragma unroll
            for (int i = 0; i < 8; ++i) {
                int r = (i < 4) ? (tr * 4 + i) : (64 + tr * 4 + (i - 4));
                xv[i] = *(const float4*)&xs[r * 68 + k];
            }
#pragma unroll
            for (int d = 0; d < 4; ++d) {
                float4 wA = *(const float4*)&ws[(k + d) * 128 + tc * 4];
                float4 wB = *(const float4*)&ws[(k + d) * 128 + 64 + tc * 4];
#pragma unroll
                for (int i = 0; i < 8; ++i) {
                    float xd = (d == 0) ? xv[i].x : (d == 1) ? xv[i].y : (d == 2) ? xv[i].z : xv[i].w;
                    acc[i][0] += xd * wA.x;
                    acc[i][1] += xd * wA.y;
                    acc[i][2] += xd * wA.z;
                    acc[i][3] += xd * wA.w;
                    acc[i][4] += xd * wB.x;
                    acc[i][5] += xd * wB.y;
                    acc[i][6] += xd * wB.z;
                    acc[i][7] += xd * wB.w;
                }
            }
        }
        __syncthreads();
    }

#pragma unroll
    for (int i = 0; i < 8; ++i) {
        int r = rowBase + ((i < 4) ? (tr * 4 + i) : (64 + tr * 4 + (i - 4)));
        if (r < n) {
            float4 oA, oB;
            oA.x = acc[i][0]; oA.y = acc[i][1]; oA.z = acc[i][2]; oA.w = acc[i][3];
            oB.x = acc[i][4]; oB.y = acc[i][5]; oB.z = acc[i][6]; oB.w = acc[i][7];
            *(float4*)&Out[(size_t)r * 128 + tc * 4]      = oA;
            *(float4*)&Out[(size_t)r * 128 + 64 + tc * 4] = oB;
        }
    }
}

// ---------------------------------------------------------------------------
// Aggregation: Out[n] = relu( dis[n]*sum_e H[src_e]*dis[src_e] + H[n]*dis[n]^2 + b )
// ---------------------------------------------------------------------------
__global__ __launch_bounds__(256) void aggregate_kernel(const float* __restrict__ H,
                                                        const float* __restrict__ dis,
                                                        const int* __restrict__ rowptr,
                                                        const int* __restrict__ csr_src,
                                                        const float* __restrict__ bias,
                                                        float* __restrict__ Out, int n) {
    const int g = threadIdx.x >> 5;
    const int l = threadIdx.x & 31;
    const int node = blockIdx.x * 8 + g;
    if (node >= n) return;

    const float dn = dis[node];
    const float4 hn = *(const float4*)&H[(size_t)node * 128 + l * 4];
    const int e0 = rowptr[node];
    const int e1 = rowptr[node + 1];

    float sx = 0.f, sy = 0.f, sz = 0.f, sw = 0.f;
    for (int e = e0; e < e1; ++e) {
        int s = csr_src[e];
        float w = dis[s];
        float4 hv = *(const float4*)&H[(size_t)s * 128 + l * 4];
        sx += hv.x * w; sy += hv.y * w; sz += hv.z * w; sw += hv.w * w;
    }
    const float self = dn * dn;
    const float4 b = *(const float4*)&bias[l * 4];
    float4 o;
    o.x = fmaxf(sx * dn + hn.x * self + b.x, 0.0f);
    o.y = fmaxf(sy * dn + hn.y * self + b.y, 0.0f);
    o.z = fmaxf(sz * dn + hn.z * self + b.z, 0.0f);
    o.w = fmaxf(sw * dn + hn.w * self + b.w, 0.0f);
    *(float4*)&Out[(size_t)node * 128 + l * 4] = o;
}

// ---------------------------------------------------------------------------
// Mean pool (sorted batch, binary-searched bounds) + 128x10 linear, per graph.
// ---------------------------------------------------------------------------
__global__ __launch_bounds__(128) void pool_kernel(const float* __restrict__ X,
                                                   const int* __restrict__ batch,
                                                   const float* __restrict__ lw,
                                                   const float* __restrict__ lb,
                                                   float* __restrict__ out, int n) {
    const int gph = blockIdx.x;
    int lo = 0, hi = n;
    while (lo < hi) { int mid = (lo + hi) >> 1; if (batch[mid] < gph) lo = mid + 1; else hi = mid; }
    const int s = lo;
    hi = n;
    while (lo < hi) { int mid = (lo + hi) >> 1; if (batch[mid] < gph + 1) lo = mid + 1; else hi = mid; }
    const int e = lo;

    const int t = threadIdx.x;
    float sum = 0.0f;
    for (int i = s; i < e; ++i) sum += X[(size_t)i * 128 + t];
    __shared__ float pl[128];
    pl[t] = sum / fmaxf((float)(e - s), 1.0f);
    __syncthreads();
    if (t < 10) {
        float acc = lb[t];
#pragma unroll 16
        for (int d = 0; d < 128; ++d) acc += pl[d] * lw[d * 10 + t];
        out[gph * 10 + t] = acc;
    }
}

// ---------------------------------------------------------------------------
extern "C" void kernel_launch(void* const* d_in, const int* in_sizes, int n_in,
                              void* d_out, int out_size, void* d_ws, size_t ws_size,
                              hipStream_t stream) {
    const int*   tokens = (const int*)d_in[0];
    const int*   eidx   = (const int*)d_in[1];
    const int*   batch  = (const int*)d_in[2];
    const float* emb    = (const float*)d_in[3];
    const float* w1     = (const float*)d_in[4];
    const float* b1     = (const float*)d_in[5];
    const float* w2     = (const float*)d_in[6];
    const float* b2     = (const float*)d_in[7];
    const float* lw     = (const float*)d_in[8];
    const float* lbv    = (const float*)d_in[9];

    const int N = in_sizes[0];
    const int E = in_sizes[1] / 2;
    const int G = out_size / 10;
    const int* src = eidx;
    const int* dst = eidx + E;

    char* p = (char*)d_ws;
    auto alloc = [&](size_t bytes) { void* r = (void*)p; p += (bytes + 255) & ~(size_t)255; return r; };
    float* dis    = (float*)alloc((size_t)N * 4);
    int*   cnt    = (int*)  alloc((size_t)N * 4);
    int*   rowptr = (int*)  alloc(((size_t)N + 1) * 4);
    int*   tmp    = (int*)  alloc((size_t)N * 4);
    int*   bsum   = (int*)  alloc(1024 * 4);
    int*   csr    = (int*)  alloc((size_t)E * 4);
    float* A      = (float*)alloc((size_t)N * 128 * 4);
    float* B      = (float*)alloc((size_t)N * 128 * 4);

    hipMemsetAsync(cnt, 0, (size_t)N * 4, stream);
    hipMemsetAsync(tmp, 0, (size_t)N * 4, stream);

    const int SB = (N + 1023) / 1024;   // scan blocks (1024 elems each)

    hist_kernel<<<(E + 255) / 256, 256, 0, stream>>>(dst, cnt, E);
    scan1_kernel<<<SB, 256, 0, stream>>>(cnt, rowptr, bsum, dis, N);
    scan2_kernel<<<1, 64, 0, stream>>>(bsum, SB);
    scan3_kernel<<<(N + 255) / 256, 256, 0, stream>>>(bsum, rowptr, N, SB);
    scatter_kernel<<<(E + 255) / 256, 256, 0, stream>>>(src, dst, rowptr, tmp, csr, E);

    // layer 1: H = emb[tokens] @ w1 ; X2 = relu(agg(H) + b1)
    gemm128<<<(N + 127) / 128, 256, 0, stream>>>(nullptr, tokens, emb, w1, A, N);
    aggregate_kernel<<<(N + 7) / 8, 256, 0, stream>>>(A, dis, rowptr, csr, b1, B, N);

    // layer 2: H2 = X2 @ w2 ; X3 = relu(agg(H2) + b2)
    gemm128<<<(N + 127) / 128, 256, 0, stream>>>(B, nullptr, nullptr, w2, A, N);
    aggregate_kernel<<<(N + 7) / 8, 256, 0, stream>>>(A, dis, rowptr, csr, b2, B, N);

    // mean pool + classifier
    pool_kernel<<<G, 128, 0, stream>>>(B, batch, lw, lbv, (float*)d_out, N);
}

// Round 3
// 344.006 us; speedup vs baseline: 1.2985x; 1.0507x over previous
//
#include <hip/hip_runtime.h>
#include <hip/hip_bf16.h>

// ---------------------------------------------------------------------------
// GCN classifier: emb-gather -> GCNConv(relu) -> GCNConv(relu) -> mean-pool ->
// linear.  All f32.  CSR built on-device each call.
// R1: 3-phase multi-block scan (90us single-block scan removed).
// R2: aggregate edge loop unrolled x4 with batched index/dis/row prefetch
//     (was a serial dependent chain: idx -> dis/row, one gather in flight).
// ---------------------------------------------------------------------------

__global__ void hist_kernel(const int* __restrict__ dst, int* __restrict__ cnt, int E) {
    int i = blockIdx.x * blockDim.x + threadIdx.x;
    if (i < E) atomicAdd(&cnt[dst[i]], 1);
}

__global__ __launch_bounds__(256) void scan1_kernel(const int* __restrict__ cnt,
                                                    int* __restrict__ rowptr,
                                                    int* __restrict__ bsum,
                                                    float* __restrict__ dis, int n) {
    __shared__ int ls[256];
    const int t = threadIdx.x;
    const int base = blockIdx.x * 1024 + t * 4;
    int v0 = 0, v1 = 0, v2 = 0, v3 = 0;
    if (base + 3 < n) {
        int4 q = *(const int4*)&cnt[base];
        v0 = q.x; v1 = q.y; v2 = q.z; v3 = q.w;
    } else {
        if (base + 0 < n) v0 = cnt[base + 0];
        if (base + 1 < n) v1 = cnt[base + 1];
        if (base + 2 < n) v2 = cnt[base + 2];
        if (base + 3 < n) v3 = cnt[base + 3];
    }
    if (base + 0 < n) dis[base + 0] = rsqrtf((float)v0 + 1.0f);
    if (base + 1 < n) dis[base + 1] = rsqrtf((float)v1 + 1.0f);
    if (base + 2 < n) dis[base + 2] = rsqrtf((float)v2 + 1.0f);
    if (base + 3 < n) dis[base + 3] = rsqrtf((float)v3 + 1.0f);

    ls[t] = v0 + v1 + v2 + v3;
    __syncthreads();
    for (int off = 1; off < 256; off <<= 1) {
        int x = (t >= off) ? ls[t - off] : 0;
        __syncthreads();
        ls[t] += x;
        __syncthreads();
    }
    int run = (t == 0) ? 0 : ls[t - 1];
    if (base + 0 < n) { rowptr[base + 0] = run; run += v0; }
    if (base + 1 < n) { rowptr[base + 1] = run; run += v1; }
    if (base + 2 < n) { rowptr[base + 2] = run; run += v2; }
    if (base + 3 < n) { rowptr[base + 3] = run; run += v3; }
    if (t == 255) bsum[blockIdx.x] = ls[255];
}

__global__ void scan2_kernel(int* __restrict__ bsum, int B) {
    if (threadIdx.x == 0 && blockIdx.x == 0) {
        int run = 0;
        for (int i = 0; i < B; ++i) { int v = bsum[i]; bsum[i] = run; run += v; }
        bsum[B] = run;
    }
}

__global__ __launch_bounds__(256) void scan3_kernel(const int* __restrict__ bsum,
                                                    int* __restrict__ rowptr, int n, int B) {
    int i = blockIdx.x * blockDim.x + threadIdx.x;
    if (i < n) rowptr[i] += bsum[i >> 10];
    if (i == 0) rowptr[n] = bsum[B];
}

__global__ void scatter_kernel(const int* __restrict__ src, const int* __restrict__ dst,
                               const int* __restrict__ rowptr, int* __restrict__ tmp,
                               int* __restrict__ csr_src, int E) {
    int i = blockIdx.x * blockDim.x + threadIdx.x;
    if (i < E) {
        int d = dst[i];
        int pos = rowptr[d] + atomicAdd(&tmp[d], 1);
        csr_src[pos] = src[i];
    }
}

// ---------------------------------------------------------------------------
// GEMM: Out[n,128] = X[n,128] @ W[128,128]
// ---------------------------------------------------------------------------
__global__ __launch_bounds__(256) void gemm128(const float* __restrict__ X,
                                               const int* __restrict__ tokens,
                                               const float* __restrict__ emb,
                                               const float* __restrict__ W,
                                               float* __restrict__ Out, int n) {
    __shared__ float ws[64 * 128];
    __shared__ float xs[128 * 68];
    const int tid = threadIdx.x;
    const int tc = tid & 15;
    const int tr = tid >> 4;
    const int rowBase = blockIdx.x * 128;

    float acc[8][8];
#pragma unroll
    for (int i = 0; i < 8; ++i)
#pragma unroll
        for (int j = 0; j < 8; ++j) acc[i][j] = 0.0f;

    for (int kk = 0; kk < 128; kk += 64) {
#pragma unroll
        for (int t = 0; t < 8; ++t) {
            int flat4 = t * 256 + tid;
            int r  = flat4 >> 5;
            int c4 = (flat4 & 31) * 4;
            *(float4*)&ws[r * 128 + c4] = *(const float4*)&W[(kk + r) * 128 + c4];
        }
#pragma unroll
        for (int t = 0; t < 8; ++t) {
            int flat4 = t * 256 + tid;
            int r  = flat4 >> 4;
            int k4 = (flat4 & 15) * 4;
            int grow = rowBase + r;
            float4 v; v.x = v.y = v.z = v.w = 0.0f;
            if (grow < n) {
                if (X) {
                    v = *(const float4*)&X[(size_t)grow * 128 + kk + k4];
                } else {
                    int tok = tokens[grow];
                    if (tok != 0) v = *(const float4*)&emb[(size_t)tok * 128 + kk + k4];
                }
            }
            *(float4*)&xs[r * 68 + k4] = v;
        }
        __syncthreads();

#pragma unroll
        for (int kc = 0; kc < 16; ++kc) {
            const int k = kc * 4;
            float4 xv[8];
#pragma unroll
            for (int i = 0; i < 8; ++i) {
                int r = (i < 4) ? (tr * 4 + i) : (64 + tr * 4 + (i - 4));
                xv[i] = *(const float4*)&xs[r * 68 + k];
            }
#pragma unroll
            for (int d = 0; d < 4; ++d) {
                float4 wA = *(const float4*)&ws[(k + d) * 128 + tc * 4];
                float4 wB = *(const float4*)&ws[(k + d) * 128 + 64 + tc * 4];
#pragma unroll
                for (int i = 0; i < 8; ++i) {
                    float xd = (d == 0) ? xv[i].x : (d == 1) ? xv[i].y : (d == 2) ? xv[i].z : xv[i].w;
                    acc[i][0] += xd * wA.x;
                    acc[i][1] += xd * wA.y;
                    acc[i][2] += xd * wA.z;
                    acc[i][3] += xd * wA.w;
                    acc[i][4] += xd * wB.x;
                    acc[i][5] += xd * wB.y;
                    acc[i][6] += xd * wB.z;
                    acc[i][7] += xd * wB.w;
                }
            }
        }
        __syncthreads();
    }

#pragma unroll
    for (int i = 0; i < 8; ++i) {
        int r = rowBase + ((i < 4) ? (tr * 4 + i) : (64 + tr * 4 + (i - 4)));
        if (r < n) {
            float4 oA, oB;
            oA.x = acc[i][0]; oA.y = acc[i][1]; oA.z = acc[i][2]; oA.w = acc[i][3];
            oB.x = acc[i][4]; oB.y = acc[i][5]; oB.z = acc[i][6]; oB.w = acc[i][7];
            *(float4*)&Out[(size_t)r * 128 + tc * 4]      = oA;
            *(float4*)&Out[(size_t)r * 128 + 64 + tc * 4] = oB;
        }
    }
}

// ---------------------------------------------------------------------------
// Aggregation, unrolled x4: Out[n] = relu( dn*sum_e H[src]*dis[src] + H[n]*dn^2 + b )
// ---------------------------------------------------------------------------
__global__ __launch_bounds__(256) void aggregate_kernel(const float* __restrict__ H,
                                                        const float* __restrict__ dis,
                                                        const int* __restrict__ rowptr,
                                                        const int* __restrict__ csr_src,
                                                        const float* __restrict__ bias,
                                                        float* __restrict__ Out, int n) {
    const int g = threadIdx.x >> 5;
    const int l = threadIdx.x & 31;
    const int node = blockIdx.x * 8 + g;
    if (node >= n) return;

    const float dn = dis[node];
    const float4 hn = *(const float4*)&H[(size_t)node * 128 + l * 4];
    const int e0 = rowptr[node];
    const int e1 = rowptr[node + 1];

    float sx = 0.f, sy = 0.f, sz = 0.f, sw = 0.f;
    int e = e0;
    for (; e + 4 <= e1; e += 4) {
        // batch the dependent loads: 4 indices, then 4 weights, then 4 rows
        const int s0 = csr_src[e + 0];
        const int s1 = csr_src[e + 1];
        const int s2 = csr_src[e + 2];
        const int s3 = csr_src[e + 3];
        const float w0 = dis[s0];
        const float w1 = dis[s1];
        const float w2 = dis[s2];
        const float w3 = dis[s3];
        const float4 h0 = *(const float4*)&H[(size_t)s0 * 128 + l * 4];
        const float4 h1 = *(const float4*)&H[(size_t)s1 * 128 + l * 4];
        const float4 h2 = *(const float4*)&H[(size_t)s2 * 128 + l * 4];
        const float4 h3 = *(const float4*)&H[(size_t)s3 * 128 + l * 4];
        sx += h0.x * w0 + h1.x * w1 + h2.x * w2 + h3.x * w3;
        sy += h0.y * w0 + h1.y * w1 + h2.y * w2 + h3.y * w3;
        sz += h0.z * w0 + h1.z * w1 + h2.z * w2 + h3.z * w3;
        sw += h0.w * w0 + h1.w * w1 + h2.w * w2 + h3.w * w3;
    }
    for (; e < e1; ++e) {
        const int s = csr_src[e];
        const float w = dis[s];
        const float4 hv = *(const float4*)&H[(size_t)s * 128 + l * 4];
        sx += hv.x * w; sy += hv.y * w; sz += hv.z * w; sw += hv.w * w;
    }
    const float self = dn * dn;
    const float4 b = *(const float4*)&bias[l * 4];
    float4 o;
    o.x = fmaxf(sx * dn + hn.x * self + b.x, 0.0f);
    o.y = fmaxf(sy * dn + hn.y * self + b.y, 0.0f);
    o.z = fmaxf(sz * dn + hn.z * self + b.z, 0.0f);
    o.w = fmaxf(sw * dn + hn.w * self + b.w, 0.0f);
    *(float4*)&Out[(size_t)node * 128 + l * 4] = o;
}

// ---------------------------------------------------------------------------
// Mean pool + 128x10 linear.
// ---------------------------------------------------------------------------
__global__ __launch_bounds__(128) void pool_kernel(const float* __restrict__ X,
                                                   const int* __restrict__ batch,
                                                   const float* __restrict__ lw,
                                                   const float* __restrict__ lb,
                                                   float* __restrict__ out, int n) {
    const int gph = blockIdx.x;
    int lo = 0, hi = n;
    while (lo < hi) { int mid = (lo + hi) >> 1; if (batch[mid] < gph) lo = mid + 1; else hi = mid; }
    const int s = lo;
    hi = n;
    while (lo < hi) { int mid = (lo + hi) >> 1; if (batch[mid] < gph + 1) lo = mid + 1; else hi = mid; }
    const int e = lo;

    const int t = threadIdx.x;
    float sum = 0.0f;
    for (int i = s; i < e; ++i) sum += X[(size_t)i * 128 + t];
    __shared__ float pl[128];
    pl[t] = sum / fmaxf((float)(e - s), 1.0f);
    __syncthreads();
    if (t < 10) {
        float acc = lb[t];
#pragma unroll 16
        for (int d = 0; d < 128; ++d) acc += pl[d] * lw[d * 10 + t];
        out[gph * 10 + t] = acc;
    }
}

// ---------------------------------------------------------------------------
extern "C" void kernel_launch(void* const* d_in, const int* in_sizes, int n_in,
                              void* d_out, int out_size, void* d_ws, size_t ws_size,
                              hipStream_t stream) {
    const int*   tokens = (const int*)d_in[0];
    const int*   eidx   = (const int*)d_in[1];
    const int*   batch  = (const int*)d_in[2];
    const float* emb    = (const float*)d_in[3];
    const float* w1     = (const float*)d_in[4];
    const float* b1     = (const float*)d_in[5];
    const float* w2     = (const float*)d_in[6];
    const float* b2     = (const float*)d_in[7];
    const float* lw     = (const float*)d_in[8];
    const float* lbv    = (const float*)d_in[9];

    const int N = in_sizes[0];
    const int E = in_sizes[1] / 2;
    const int G = out_size / 10;
    const int* src = eidx;
    const int* dst = eidx + E;

    char* p = (char*)d_ws;
    auto alloc = [&](size_t bytes) { void* r = (void*)p; p += (bytes + 255) & ~(size_t)255; return r; };
    float* dis    = (float*)alloc((size_t)N * 4);
    int*   cnt    = (int*)  alloc((size_t)N * 4);
    int*   rowptr = (int*)  alloc(((size_t)N + 1) * 4);
    int*   tmp    = (int*)  alloc((size_t)N * 4);
    int*   bsum   = (int*)  alloc(1024 * 4);
    int*   csr    = (int*)  alloc((size_t)E * 4);
    float* A      = (float*)alloc((size_t)N * 128 * 4);
    float* B      = (float*)alloc((size_t)N * 128 * 4);

    hipMemsetAsync(cnt, 0, (size_t)N * 4, stream);
    hipMemsetAsync(tmp, 0, (size_t)N * 4, stream);

    const int SB = (N + 1023) / 1024;

    hist_kernel<<<(E + 255) / 256, 256, 0, stream>>>(dst, cnt, E);
    scan1_kernel<<<SB, 256, 0, stream>>>(cnt, rowptr, bsum, dis, N);
    scan2_kernel<<<1, 64, 0, stream>>>(bsum, SB);
    scan3_kernel<<<(N + 255) / 256, 256, 0, stream>>>(bsum, rowptr, N, SB);
    scatter_kernel<<<(E + 255) / 256, 256, 0, stream>>>(src, dst, rowptr, tmp, csr, E);

    gemm128<<<(N + 127) / 128, 256, 0, stream>>>(nullptr, tokens, emb, w1, A, N);
    aggregate_kernel<<<(N + 7) / 8, 256, 0, stream>>>(A, dis, rowptr, csr, b1, B, N);

    gemm128<<<(N + 127) / 128, 256, 0, stream>>>(B, nullptr, nullptr, w2, A, N);
    aggregate_kernel<<<(N + 7) / 8, 256, 0, stream>>>(A, dis, rowptr, csr, b2, B, N);

    pool_kernel<<<G, 128, 0, stream>>>(B, batch, lw, lbv, (float*)d_out, N);
}

// Round 4
// 281.606 us; speedup vs baseline: 1.5863x; 1.2216x over previous
//
#include <hip/hip_runtime.h>
#include <hip/hip_bf16.h>

// ---------------------------------------------------------------------------
// GCN classifier.  R1: multi-block scan.  R2: agg unroll x4.
// R3: bf16 inter-layer activations (halves gather traffic, the dominant cost)
//     + 64-row GEMM tiles (49KB LDS -> 3 blocks/CU; was 66KB -> 1.5 blocks/CU,
//     7.7% occupancy).
// ---------------------------------------------------------------------------

typedef unsigned int uint;
typedef unsigned short ushort;

__device__ inline float bf_lo(uint u) { return __uint_as_float(u << 16); }
__device__ inline float bf_hi(uint u) { return __uint_as_float(u & 0xffff0000u); }
__device__ inline ushort f2bf(float f) {           // round-to-nearest-even
    uint u = __float_as_uint(f);
    return (ushort)((u + 0x7fffu + ((u >> 16) & 1u)) >> 16);
}
__device__ inline uint pack2bf(float a, float b) {
    return (uint)f2bf(a) | ((uint)f2bf(b) << 16);
}

__global__ void hist_kernel(const int* __restrict__ dst, int* __restrict__ cnt, int E) {
    int i = blockIdx.x * blockDim.x + threadIdx.x;
    if (i < E) atomicAdd(&cnt[dst[i]], 1);
}

__global__ __launch_bounds__(256) void scan1_kernel(const int* __restrict__ cnt,
                                                    int* __restrict__ rowptr,
                                                    int* __restrict__ bsum,
                                                    float* __restrict__ dis, int n) {
    __shared__ int ls[256];
    const int t = threadIdx.x;
    const int base = blockIdx.x * 1024 + t * 4;
    int v0 = 0, v1 = 0, v2 = 0, v3 = 0;
    if (base + 3 < n) {
        int4 q = *(const int4*)&cnt[base];
        v0 = q.x; v1 = q.y; v2 = q.z; v3 = q.w;
    } else {
        if (base + 0 < n) v0 = cnt[base + 0];
        if (base + 1 < n) v1 = cnt[base + 1];
        if (base + 2 < n) v2 = cnt[base + 2];
        if (base + 3 < n) v3 = cnt[base + 3];
    }
    if (base + 0 < n) dis[base + 0] = rsqrtf((float)v0 + 1.0f);
    if (base + 1 < n) dis[base + 1] = rsqrtf((float)v1 + 1.0f);
    if (base + 2 < n) dis[base + 2] = rsqrtf((float)v2 + 1.0f);
    if (base + 3 < n) dis[base + 3] = rsqrtf((float)v3 + 1.0f);

    ls[t] = v0 + v1 + v2 + v3;
    __syncthreads();
    for (int off = 1; off < 256; off <<= 1) {
        int x = (t >= off) ? ls[t - off] : 0;
        __syncthreads();
        ls[t] += x;
        __syncthreads();
    }
    int run = (t == 0) ? 0 : ls[t - 1];
    if (base + 0 < n) { rowptr[base + 0] = run; run += v0; }
    if (base + 1 < n) { rowptr[base + 1] = run; run += v1; }
    if (base + 2 < n) { rowptr[base + 2] = run; run += v2; }
    if (base + 3 < n) { rowptr[base + 3] = run; run += v3; }
    if (t == 255) bsum[blockIdx.x] = ls[255];
}

__global__ void scan2_kernel(int* __restrict__ bsum, int B) {
    if (threadIdx.x == 0 && blockIdx.x == 0) {
        int run = 0;
        for (int i = 0; i < B; ++i) { int v = bsum[i]; bsum[i] = run; run += v; }
        bsum[B] = run;
    }
}

__global__ __launch_bounds__(256) void scan3_kernel(const int* __restrict__ bsum,
                                                    int* __restrict__ rowptr, int n, int B) {
    int i = blockIdx.x * blockDim.x + threadIdx.x;
    if (i < n) rowptr[i] += bsum[i >> 10];
    if (i == 0) rowptr[n] = bsum[B];
}

__global__ void scatter_kernel(const int* __restrict__ src, const int* __restrict__ dst,
                               const int* __restrict__ rowptr, int* __restrict__ tmp,
                               int* __restrict__ csr_src, int E) {
    int i = blockIdx.x * blockDim.x + threadIdx.x;
    if (i < E) {
        int d = dst[i];
        int pos = rowptr[d] + atomicAdd(&tmp[d], 1);
        csr_src[pos] = src[i];
    }
}

// ---------------------------------------------------------------------------
// GEMM: Out_bf16[n,128] = X[n,128] @ W[128,128]
// A-input: if Xbf != nullptr, bf16 rows; else emb-gather (f32, padding_idx=0).
// Tile 64 rows x 128 cols, 256 threads, acc[4][8]/thread.
// LDS = ws 32KB + xs 17.4KB = 49.4KB -> 3 blocks/CU.
// ---------------------------------------------------------------------------
__global__ __launch_bounds__(256) void gemm128(const ushort* __restrict__ Xbf,
                                               const int* __restrict__ tokens,
                                               const float* __restrict__ emb,
                                               const float* __restrict__ W,
                                               ushort* __restrict__ Out, int n) {
    __shared__ float ws[64 * 128];
    __shared__ float xs[64 * 68];
    const int tid = threadIdx.x;
    const int tc = tid & 15;
    const int tr = tid >> 4;
    const int rowBase = blockIdx.x * 64;

    float acc[4][8];
#pragma unroll
    for (int i = 0; i < 4; ++i)
#pragma unroll
        for (int j = 0; j < 8; ++j) acc[i][j] = 0.0f;

    for (int kk = 0; kk < 128; kk += 64) {
        // ---- stage W k-slice: 64 x 128 f32 (2048 float4, 8/thread)
#pragma unroll
        for (int t = 0; t < 8; ++t) {
            int flat4 = t * 256 + tid;
            int r  = flat4 >> 5;
            int c4 = (flat4 & 31) * 4;
            *(float4*)&ws[r * 128 + c4] = *(const float4*)&W[(kk + r) * 128 + c4];
        }
        // ---- stage X slice: 64 rows x 64 k
        if (Xbf) {
            // bf16 input: 512 uint4 (8 bf16 each), 2/thread
#pragma unroll
            for (int t = 0; t < 2; ++t) {
                int flat = t * 256 + tid;
                int r  = flat >> 3;
                int c8 = (flat & 7) * 8;
                int grow = rowBase + r;
                float4 a, b;
                if (grow < n) {
                    uint4 q = *(const uint4*)(Xbf + (size_t)grow * 128 + kk + c8);
                    a.x = bf_lo(q.x); a.y = bf_hi(q.x); a.z = bf_lo(q.y); a.w = bf_hi(q.y);
                    b.x = bf_lo(q.z); b.y = bf_hi(q.z); b.z = bf_lo(q.w); b.w = bf_hi(q.w);
                } else {
                    a.x=a.y=a.z=a.w=0.f; b = a;
                }
                *(float4*)&xs[r * 68 + c8]     = a;
                *(float4*)&xs[r * 68 + c8 + 4] = b;
            }
        } else {
            // emb gather f32: 1024 float4, 4/thread
#pragma unroll
            for (int t = 0; t < 4; ++t) {
                int flat4 = t * 256 + tid;
                int r  = flat4 >> 4;
                int k4 = (flat4 & 15) * 4;
                int grow = rowBase + r;
                float4 v; v.x = v.y = v.z = v.w = 0.0f;
                if (grow < n) {
                    int tok = tokens[grow];
                    if (tok != 0) v = *(const float4*)&emb[(size_t)tok * 128 + kk + k4];
                }
                *(float4*)&xs[r * 68 + k4] = v;
            }
        }
        __syncthreads();

#pragma unroll
        for (int kc = 0; kc < 16; ++kc) {
            const int k = kc * 4;
            float4 xv[4];
#pragma unroll
            for (int i = 0; i < 4; ++i)
                xv[i] = *(const float4*)&xs[(tr * 4 + i) * 68 + k];
#pragma unroll
            for (int d = 0; d < 4; ++d) {
                float4 wA = *(const float4*)&ws[(k + d) * 128 + tc * 4];
                float4 wB = *(const float4*)&ws[(k + d) * 128 + 64 + tc * 4];
#pragma unroll
                for (int i = 0; i < 4; ++i) {
                    float xd = (d == 0) ? xv[i].x : (d == 1) ? xv[i].y : (d == 2) ? xv[i].z : xv[i].w;
                    acc[i][0] += xd * wA.x;
                    acc[i][1] += xd * wA.y;
                    acc[i][2] += xd * wA.z;
                    acc[i][3] += xd * wA.w;
                    acc[i][4] += xd * wB.x;
                    acc[i][5] += xd * wB.y;
                    acc[i][6] += xd * wB.z;
                    acc[i][7] += xd * wB.w;
                }
            }
        }
        __syncthreads();
    }

#pragma unroll
    for (int i = 0; i < 4; ++i) {
        int r = rowBase + tr * 4 + i;
        if (r < n) {
            uint2 pA, pB;
            pA.x = pack2bf(acc[i][0], acc[i][1]);
            pA.y = pack2bf(acc[i][2], acc[i][3]);
            pB.x = pack2bf(acc[i][4], acc[i][5]);
            pB.y = pack2bf(acc[i][6], acc[i][7]);
            *(uint2*)(Out + (size_t)r * 128 + tc * 4)      = pA;
            *(uint2*)(Out + (size_t)r * 128 + 64 + tc * 4) = pB;
        }
    }
}

// ---------------------------------------------------------------------------
// Aggregation over bf16 H: Out = relu( dn*sum_e H[src]*dis[src] + H[n]*dn^2 + b )
// 16 lanes/node (8 cols each, uint4 = 8 bf16), 16 nodes / 256-thread block.
// OUT_BF16: layer-1 output (feeds gemm2); else f32 (feeds pool).
// ---------------------------------------------------------------------------
template<bool OUT_BF16>
__global__ __launch_bounds__(256) void aggregate_kernel(const ushort* __restrict__ H,
                                                        const float* __restrict__ dis,
                                                        const int* __restrict__ rowptr,
                                                        const int* __restrict__ csr_src,
                                                        const float* __restrict__ bias,
                                                        void* __restrict__ OutV, int n) {
    const int g = threadIdx.x >> 4;
    const int l = threadIdx.x & 15;
    const int node = blockIdx.x * 16 + g;
    if (node >= n) return;

    const float dn = dis[node];
    const uint4 hq = *(const uint4*)(H + (size_t)node * 128 + l * 8);
    const int e0 = rowptr[node];
    const int e1 = rowptr[node + 1];

    float s0_ = 0.f, s1_ = 0.f, s2_ = 0.f, s3_ = 0.f,
          s4_ = 0.f, s5_ = 0.f, s6_ = 0.f, s7_ = 0.f;

    int e = e0;
    for (; e + 4 <= e1; e += 4) {
        const int a0 = csr_src[e + 0];
        const int a1 = csr_src[e + 1];
        const int a2 = csr_src[e + 2];
        const int a3 = csr_src[e + 3];
        const float w0 = dis[a0];
        const float w1 = dis[a1];
        const float w2 = dis[a2];
        const float w3 = dis[a3];
        const uint4 h0 = *(const uint4*)(H + (size_t)a0 * 128 + l * 8);
        const uint4 h1 = *(const uint4*)(H + (size_t)a1 * 128 + l * 8);
        const uint4 h2 = *(const uint4*)(H + (size_t)a2 * 128 + l * 8);
        const uint4 h3 = *(const uint4*)(H + (size_t)a3 * 128 + l * 8);
        s0_ += bf_lo(h0.x)*w0 + bf_lo(h1.x)*w1 + bf_lo(h2.x)*w2 + bf_lo(h3.x)*w3;
        s1_ += bf_hi(h0.x)*w0 + bf_hi(h1.x)*w1 + bf_hi(h2.x)*w2 + bf_hi(h3.x)*w3;
        s2_ += bf_lo(h0.y)*w0 + bf_lo(h1.y)*w1 + bf_lo(h2.y)*w2 + bf_lo(h3.y)*w3;
        s3_ += bf_hi(h0.y)*w0 + bf_hi(h1.y)*w1 + bf_hi(h2.y)*w2 + bf_hi(h3.y)*w3;
        s4_ += bf_lo(h0.z)*w0 + bf_lo(h1.z)*w1 + bf_lo(h2.z)*w2 + bf_lo(h3.z)*w3;
        s5_ += bf_hi(h0.z)*w0 + bf_hi(h1.z)*w1 + bf_hi(h2.z)*w2 + bf_hi(h3.z)*w3;
        s6_ += bf_lo(h0.w)*w0 + bf_lo(h1.w)*w1 + bf_lo(h2.w)*w2 + bf_lo(h3.w)*w3;
        s7_ += bf_hi(h0.w)*w0 + bf_hi(h1.w)*w1 + bf_hi(h2.w)*w2 + bf_hi(h3.w)*w3;
    }
    for (; e < e1; ++e) {
        const int a = csr_src[e];
        const float w = dis[a];
        const uint4 h = *(const uint4*)(H + (size_t)a * 128 + l * 8);
        s0_ += bf_lo(h.x)*w; s1_ += bf_hi(h.x)*w;
        s2_ += bf_lo(h.y)*w; s3_ += bf_hi(h.y)*w;
        s4_ += bf_lo(h.z)*w; s5_ += bf_hi(h.z)*w;
        s6_ += bf_lo(h.w)*w; s7_ += bf_hi(h.w)*w;
    }

    const float self = dn * dn;
    const float4 bA = *(const float4*)&bias[l * 8];
    const float4 bB = *(const float4*)&bias[l * 8 + 4];
    float o0 = fmaxf(s0_ * dn + bf_lo(hq.x) * self + bA.x, 0.0f);
    float o1 = fmaxf(s1_ * dn + bf_hi(hq.x) * self + bA.y, 0.0f);
    float o2 = fmaxf(s2_ * dn + bf_lo(hq.y) * self + bA.z, 0.0f);
    float o3 = fmaxf(s3_ * dn + bf_hi(hq.y) * self + bA.w, 0.0f);
    float o4 = fmaxf(s4_ * dn + bf_lo(hq.z) * self + bB.x, 0.0f);
    float o5 = fmaxf(s5_ * dn + bf_hi(hq.z) * self + bB.y, 0.0f);
    float o6 = fmaxf(s6_ * dn + bf_lo(hq.w) * self + bB.z, 0.0f);
    float o7 = fmaxf(s7_ * dn + bf_hi(hq.w) * self + bB.w, 0.0f);

    if (OUT_BF16) {
        uint4 o;
        o.x = pack2bf(o0, o1); o.y = pack2bf(o2, o3);
        o.z = pack2bf(o4, o5); o.w = pack2bf(o6, o7);
        *(uint4*)((ushort*)OutV + (size_t)node * 128 + l * 8) = o;
    } else {
        float4 oa, ob;
        oa.x = o0; oa.y = o1; oa.z = o2; oa.w = o3;
        ob.x = o4; ob.y = o5; ob.z = o6; ob.w = o7;
        *(float4*)((float*)OutV + (size_t)node * 128 + l * 8)     = oa;
        *(float4*)((float*)OutV + (size_t)node * 128 + l * 8 + 4) = ob;
    }
}

// ---------------------------------------------------------------------------
// Mean pool (sorted batch) + 128x10 linear.
// ---------------------------------------------------------------------------
__global__ __launch_bounds__(128) void pool_kernel(const float* __restrict__ X,
                                                   const int* __restrict__ batch,
                                                   const float* __restrict__ lw,
                                                   const float* __restrict__ lb,
                                                   float* __restrict__ out, int n) {
    const int gph = blockIdx.x;
    int lo = 0, hi = n;
    while (lo < hi) { int mid = (lo + hi) >> 1; if (batch[mid] < gph) lo = mid + 1; else hi = mid; }
    const int s = lo;
    hi = n;
    while (lo < hi) { int mid = (lo + hi) >> 1; if (batch[mid] < gph + 1) lo = mid + 1; else hi = mid; }
    const int e = lo;

    const int t = threadIdx.x;
    float sum = 0.0f;
    for (int i = s; i < e; ++i) sum += X[(size_t)i * 128 + t];
    __shared__ float pl[128];
    pl[t] = sum / fmaxf((float)(e - s), 1.0f);
    __syncthreads();
    if (t < 10) {
        float acc = lb[t];
#pragma unroll 16
        for (int d = 0; d < 128; ++d) acc += pl[d] * lw[d * 10 + t];
        out[gph * 10 + t] = acc;
    }
}

// ---------------------------------------------------------------------------
extern "C" void kernel_launch(void* const* d_in, const int* in_sizes, int n_in,
                              void* d_out, int out_size, void* d_ws, size_t ws_size,
                              hipStream_t stream) {
    const int*   tokens = (const int*)d_in[0];
    const int*   eidx   = (const int*)d_in[1];
    const int*   batch  = (const int*)d_in[2];
    const float* emb    = (const float*)d_in[3];
    const float* w1     = (const float*)d_in[4];
    const float* b1     = (const float*)d_in[5];
    const float* w2     = (const float*)d_in[6];
    const float* b2     = (const float*)d_in[7];
    const float* lw     = (const float*)d_in[8];
    const float* lbv    = (const float*)d_in[9];

    const int N = in_sizes[0];
    const int E = in_sizes[1] / 2;
    const int G = out_size / 10;
    const int* src = eidx;
    const int* dst = eidx + E;

    char* p = (char*)d_ws;
    auto alloc = [&](size_t bytes) { void* r = (void*)p; p += (bytes + 255) & ~(size_t)255; return r; };
    float*  dis    = (float*)alloc((size_t)N * 4);
    int*    cnt    = (int*)  alloc((size_t)N * 4);
    int*    rowptr = (int*)  alloc(((size_t)N + 1) * 4);
    int*    tmp    = (int*)  alloc((size_t)N * 4);
    int*    bsum   = (int*)  alloc(1024 * 4);
    int*    csr    = (int*)  alloc((size_t)E * 4);
    ushort* A      = (ushort*)alloc((size_t)N * 128 * 2);   // H (bf16)
    ushort* B      = (ushort*)alloc((size_t)N * 128 * 2);   // X2 (bf16)
    float*  C      = (float*) alloc((size_t)N * 128 * 4);   // X3 (f32)

    hipMemsetAsync(cnt, 0, (size_t)N * 4, stream);
    hipMemsetAsync(tmp, 0, (size_t)N * 4, stream);

    const int SB = (N + 1023) / 1024;

    hist_kernel<<<(E + 255) / 256, 256, 0, stream>>>(dst, cnt, E);
    scan1_kernel<<<SB, 256, 0, stream>>>(cnt, rowptr, bsum, dis, N);
    scan2_kernel<<<1, 64, 0, stream>>>(bsum, SB);
    scan3_kernel<<<(N + 255) / 256, 256, 0, stream>>>(bsum, rowptr, N, SB);
    scatter_kernel<<<(E + 255) / 256, 256, 0, stream>>>(src, dst, rowptr, tmp, csr, E);

    // layer 1: H = emb[tokens] @ w1 (bf16) ; X2 = relu(agg(H)+b1) (bf16)
    gemm128<<<(N + 63) / 64, 256, 0, stream>>>(nullptr, tokens, emb, w1, A, N);
    aggregate_kernel<true><<<(N + 15) / 16, 256, 0, stream>>>(A, dis, rowptr, csr, b1, B, N);

    // layer 2: H2 = X2 @ w2 (bf16) ; X3 = relu(agg(H2)+b2) (f32)
    gemm128<<<(N + 63) / 64, 256, 0, stream>>>(B, nullptr, nullptr, w2, A, N);
    aggregate_kernel<false><<<(N + 15) / 16, 256, 0, stream>>>(A, dis, rowptr, csr, b2, C, N);

    pool_kernel<<<G, 128, 0, stream>>>(C, batch, lw, lbv, (float*)d_out, N);
}

// Round 5
// 227.937 us; speedup vs baseline: 1.9598x; 1.2355x over previous
//
#include <hip/hip_runtime.h>
#include <hip/hip_bf16.h>

// ---------------------------------------------------------------------------
// GCN classifier.  R1: multi-block scan.  R2: agg unroll x4.  R3: bf16
// activations + 64-row GEMM tiles.
// R4: bucketed counting-sort CSR build. Old scatter_kernel wrote 56MB HBM
//     (17x amplification: random 4B writes + tmp atomics ping-ponging lines
//     across 8 non-coherent XCD L2s). New scheme: 256-node buckets; LDS
//     presort per block -> contiguous staged runs; per-bucket CSR scatter
//     into a 16KB L2-resident region on one CU. Also absorbs hist_kernel and
//     the node-level rowptr scan (rowptr/dis written coalesced per bucket).
//     Requires N < 2^24 (edge packed as src | dlocal<<24). N=50000 here.
// ---------------------------------------------------------------------------

typedef unsigned int uint;
typedef unsigned short ushort;

__device__ inline float bf_lo(uint u) { return __uint_as_float(u << 16); }
__device__ inline float bf_hi(uint u) { return __uint_as_float(u & 0xffff0000u); }
__device__ inline ushort f2bf(float f) {           // round-to-nearest-even
    uint u = __float_as_uint(f);
    return (ushort)((u + 0x7fffu + ((u >> 16) & 1u)) >> 16);
}
__device__ inline uint pack2bf(float a, float b) {
    return (uint)f2bf(a) | ((uint)f2bf(b) << 16);
}

#define EPB 2048   // edges per block in bucketing kernels

// ---- 1) per-bucket histogram (LDS-aggregated) -----------------------------
__global__ __launch_bounds__(256) void bucket_hist(const int* __restrict__ dst,
                                                   int* __restrict__ bcnt, int E, int NB) {
    __shared__ int lh[256];
    const int t = threadIdx.x;
    lh[t] = 0;
    __syncthreads();
    const int base = blockIdx.x * EPB;
    const int end  = min(E, base + EPB);
    for (int i = base + t; i < end; i += 256)
        atomicAdd(&lh[((uint)dst[i]) >> 8], 1);
    __syncthreads();
    if (t < NB && lh[t]) atomicAdd(&bcnt[t], lh[t]);
}

// ---- 2) scan bucket counts -> boff[0..NB]; init bcur ----------------------
__global__ __launch_bounds__(256) void bucket_scan(const int* __restrict__ bcnt,
                                                   int* __restrict__ boff,
                                                   int* __restrict__ bcur, int NB) {
    __shared__ int ls[256];
    const int t = threadIdx.x;
    int v = (t < NB) ? bcnt[t] : 0;
    ls[t] = v;
    __syncthreads();
    for (int off = 1; off < 256; off <<= 1) {
        int x = (t >= off) ? ls[t - off] : 0;
        __syncthreads();
        ls[t] += x;
        __syncthreads();
    }
    int excl = ls[t] - v;
    if (t <= NB) {
        int o = (t < NB) ? excl : ls[255];
        boff[t] = o;
        if (t < NB) bcur[t] = o;
    }
    if (t == 255 && NB < 255) boff[NB] = ls[255];   // ensure boff[NB]=E
}

// ---- 3) scatter edges into bucket-staged array (block-local presort) ------
__global__ __launch_bounds__(256) void bucket_scatter(const int* __restrict__ src,
                                                      const int* __restrict__ dst,
                                                      int* __restrict__ bcur,
                                                      uint* __restrict__ bstage,
                                                      int E, int NB) {
    __shared__ int lh[256];
    __shared__ int lbase[257];
    __shared__ int gbase[256];
    __shared__ int lcur[256];
    __shared__ uint stage[EPB];
    const int t = threadIdx.x;
    const int base = blockIdx.x * EPB;
    const int end  = min(E, base + EPB);
    const int tot  = end - base;

    lh[t] = 0;
    __syncthreads();

    uint pk[8]; int bk[8]; int cnt = 0;
    for (int i = base + t; i < end; i += 256) {
        int s = src[i];
        uint d = (uint)dst[i];
        bk[cnt] = (int)(d >> 8);
        pk[cnt] = (uint)s | ((d & 255u) << 24);
        atomicAdd(&lh[bk[cnt]], 1);
        ++cnt;
    }
    __syncthreads();

    // reserve global range per bucket for this block
    if (t < NB && lh[t]) gbase[t] = atomicAdd(&bcur[t], lh[t]);
    // exclusive scan of lh -> lbase
    {
        __shared__ int ls[256];
        int v = lh[t];
        ls[t] = v;
        __syncthreads();
        for (int off = 1; off < 256; off <<= 1) {
            int x = (t >= off) ? ls[t - off] : 0;
            __syncthreads();
            ls[t] += x;
            __syncthreads();
        }
        lbase[t] = ls[t] - v;
        if (t == 255) lbase[256] = ls[255];
        lcur[t] = 0;
    }
    __syncthreads();

    for (int j = 0; j < cnt; ++j) {
        int p = lbase[bk[j]] + atomicAdd(&lcur[bk[j]], 1);
        stage[p] = pk[j];
    }
    __syncthreads();

    // copy out grouped by bucket: contiguous run per bucket
    for (int i = t; i < tot; i += 256) {
        // find b: lbase[b] <= i < lbase[b+1]
        int lo = 0, hi = 256;
        while (lo + 1 < hi) {
            int mid = (lo + hi) >> 1;
            if (lbase[mid] <= i) lo = mid; else hi = mid;
        }
        bstage[gbase[lo] + (i - lbase[lo])] = stage[i];
    }
}

// ---- 4) per-bucket: node hist -> dis + rowptr (coalesced), then CSR -------
__global__ __launch_bounds__(256) void csr_build(const uint* __restrict__ bstage,
                                                 const int* __restrict__ boff,
                                                 float* __restrict__ dis,
                                                 int* __restrict__ rowptr,
                                                 int* __restrict__ csr,
                                                 int N, int NB, int E) {
    __shared__ int lh[256];
    __shared__ int ls[256];
    __shared__ int lbase[256];
    __shared__ int lcur[256];
    const int b = blockIdx.x;
    const int t = threadIdx.x;
    const int base  = boff[b];
    const int cntb  = boff[b + 1] - base;
    const int n0    = b << 8;
    const int nn    = min(256, N - n0);

    lh[t] = 0;
    __syncthreads();
    for (int i = t; i < cntb; i += 256)
        atomicAdd(&lh[bstage[base + i] >> 24], 1);
    __syncthreads();

    const int v = lh[t];
    ls[t] = v;
    __syncthreads();
    for (int off = 1; off < 256; off <<= 1) {
        int x = (t >= off) ? ls[t - off] : 0;
        __syncthreads();
        ls[t] += x;
        __syncthreads();
    }
    lbase[t] = ls[t] - v;     // node-local exclusive offset
    lcur[t] = 0;
    if (t < nn) {
        dis[n0 + t]    = rsqrtf((float)v + 1.0f);
        rowptr[n0 + t] = base + lbase[t];
    }
    if (b == NB - 1 && t == 0) rowptr[N] = E;
    __syncthreads();

    for (int i = t; i < cntb; i += 256) {
        uint e = bstage[base + i];
        int dl = (int)(e >> 24);
        int pos = base + lbase[dl] + atomicAdd(&lcur[dl], 1);
        csr[pos] = (int)(e & 0xFFFFFFu);
    }
}

// ---------------------------------------------------------------------------
// GEMM: Out_bf16[n,128] = X[n,128] @ W[128,128]
// ---------------------------------------------------------------------------
__global__ __launch_bounds__(256) void gemm128(const ushort* __restrict__ Xbf,
                                               const int* __restrict__ tokens,
                                               const float* __restrict__ emb,
                                               const float* __restrict__ W,
                                               ushort* __restrict__ Out, int n) {
    __shared__ float ws[64 * 128];
    __shared__ float xs[64 * 68];
    const int tid = threadIdx.x;
    const int tc = tid & 15;
    const int tr = tid >> 4;
    const int rowBase = blockIdx.x * 64;

    float acc[4][8];
#pragma unroll
    for (int i = 0; i < 4; ++i)
#pragma unroll
        for (int j = 0; j < 8; ++j) acc[i][j] = 0.0f;

    for (int kk = 0; kk < 128; kk += 64) {
#pragma unroll
        for (int t = 0; t < 8; ++t) {
            int flat4 = t * 256 + tid;
            int r  = flat4 >> 5;
            int c4 = (flat4 & 31) * 4;
            *(float4*)&ws[r * 128 + c4] = *(const float4*)&W[(kk + r) * 128 + c4];
        }
        if (Xbf) {
#pragma unroll
            for (int t = 0; t < 2; ++t) {
                int flat = t * 256 + tid;
                int r  = flat >> 3;
                int c8 = (flat & 7) * 8;
                int grow = rowBase + r;
                float4 a, b;
                if (grow < n) {
                    uint4 q = *(const uint4*)(Xbf + (size_t)grow * 128 + kk + c8);
                    a.x = bf_lo(q.x); a.y = bf_hi(q.x); a.z = bf_lo(q.y); a.w = bf_hi(q.y);
                    b.x = bf_lo(q.z); b.y = bf_hi(q.z); b.z = bf_lo(q.w); b.w = bf_hi(q.w);
                } else {
                    a.x=a.y=a.z=a.w=0.f; b = a;
                }
                *(float4*)&xs[r * 68 + c8]     = a;
                *(float4*)&xs[r * 68 + c8 + 4] = b;
            }
        } else {
#pragma unroll
            for (int t = 0; t < 4; ++t) {
                int flat4 = t * 256 + tid;
                int r  = flat4 >> 4;
                int k4 = (flat4 & 15) * 4;
                int grow = rowBase + r;
                float4 v; v.x = v.y = v.z = v.w = 0.0f;
                if (grow < n) {
                    int tok = tokens[grow];
                    if (tok != 0) v = *(const float4*)&emb[(size_t)tok * 128 + kk + k4];
                }
                *(float4*)&xs[r * 68 + k4] = v;
            }
        }
        __syncthreads();

#pragma unroll
        for (int kc = 0; kc < 16; ++kc) {
            const int k = kc * 4;
            float4 xv[4];
#pragma unroll
            for (int i = 0; i < 4; ++i)
                xv[i] = *(const float4*)&xs[(tr * 4 + i) * 68 + k];
#pragma unroll
            for (int d = 0; d < 4; ++d) {
                float4 wA = *(const float4*)&ws[(k + d) * 128 + tc * 4];
                float4 wB = *(const float4*)&ws[(k + d) * 128 + 64 + tc * 4];
#pragma unroll
                for (int i = 0; i < 4; ++i) {
                    float xd = (d == 0) ? xv[i].x : (d == 1) ? xv[i].y : (d == 2) ? xv[i].z : xv[i].w;
                    acc[i][0] += xd * wA.x;
                    acc[i][1] += xd * wA.y;
                    acc[i][2] += xd * wA.z;
                    acc[i][3] += xd * wA.w;
                    acc[i][4] += xd * wB.x;
                    acc[i][5] += xd * wB.y;
                    acc[i][6] += xd * wB.z;
                    acc[i][7] += xd * wB.w;
                }
            }
        }
        __syncthreads();
    }

#pragma unroll
    for (int i = 0; i < 4; ++i) {
        int r = rowBase + tr * 4 + i;
        if (r < n) {
            uint2 pA, pB;
            pA.x = pack2bf(acc[i][0], acc[i][1]);
            pA.y = pack2bf(acc[i][2], acc[i][3]);
            pB.x = pack2bf(acc[i][4], acc[i][5]);
            pB.y = pack2bf(acc[i][6], acc[i][7]);
            *(uint2*)(Out + (size_t)r * 128 + tc * 4)      = pA;
            *(uint2*)(Out + (size_t)r * 128 + 64 + tc * 4) = pB;
        }
    }
}

// ---------------------------------------------------------------------------
// Aggregation over bf16 H.
// ---------------------------------------------------------------------------
template<bool OUT_BF16>
__global__ __launch_bounds__(256) void aggregate_kernel(const ushort* __restrict__ H,
                                                        const float* __restrict__ dis,
                                                        const int* __restrict__ rowptr,
                                                        const int* __restrict__ csr_src,
                                                        const float* __restrict__ bias,
                                                        void* __restrict__ OutV, int n) {
    const int g = threadIdx.x >> 4;
    const int l = threadIdx.x & 15;
    const int node = blockIdx.x * 16 + g;
    if (node >= n) return;

    const float dn = dis[node];
    const uint4 hq = *(const uint4*)(H + (size_t)node * 128 + l * 8);
    const int e0 = rowptr[node];
    const int e1 = rowptr[node + 1];

    float s0_ = 0.f, s1_ = 0.f, s2_ = 0.f, s3_ = 0.f,
          s4_ = 0.f, s5_ = 0.f, s6_ = 0.f, s7_ = 0.f;

    int e = e0;
    for (; e + 4 <= e1; e += 4) {
        const int a0 = csr_src[e + 0];
        const int a1 = csr_src[e + 1];
        const int a2 = csr_src[e + 2];
        const int a3 = csr_src[e + 3];
        const float w0 = dis[a0];
        const float w1 = dis[a1];
        const float w2 = dis[a2];
        const float w3 = dis[a3];
        const uint4 h0 = *(const uint4*)(H + (size_t)a0 * 128 + l * 8);
        const uint4 h1 = *(const uint4*)(H + (size_t)a1 * 128 + l * 8);
        const uint4 h2 = *(const uint4*)(H + (size_t)a2 * 128 + l * 8);
        const uint4 h3 = *(const uint4*)(H + (size_t)a3 * 128 + l * 8);
        s0_ += bf_lo(h0.x)*w0 + bf_lo(h1.x)*w1 + bf_lo(h2.x)*w2 + bf_lo(h3.x)*w3;
        s1_ += bf_hi(h0.x)*w0 + bf_hi(h1.x)*w1 + bf_hi(h2.x)*w2 + bf_hi(h3.x)*w3;
        s2_ += bf_lo(h0.y)*w0 + bf_lo(h1.y)*w1 + bf_lo(h2.y)*w2 + bf_lo(h3.y)*w3;
        s3_ += bf_hi(h0.y)*w0 + bf_hi(h1.y)*w1 + bf_hi(h2.y)*w2 + bf_hi(h3.y)*w3;
        s4_ += bf_lo(h0.z)*w0 + bf_lo(h1.z)*w1 + bf_lo(h2.z)*w2 + bf_lo(h3.z)*w3;
        s5_ += bf_hi(h0.z)*w0 + bf_hi(h1.z)*w1 + bf_hi(h2.z)*w2 + bf_hi(h3.z)*w3;
        s6_ += bf_lo(h0.w)*w0 + bf_lo(h1.w)*w1 + bf_lo(h2.w)*w2 + bf_lo(h3.w)*w3;
        s7_ += bf_hi(h0.w)*w0 + bf_hi(h1.w)*w1 + bf_hi(h2.w)*w2 + bf_hi(h3.w)*w3;
    }
    for (; e < e1; ++e) {
        const int a = csr_src[e];
        const float w = dis[a];
        const uint4 h = *(const uint4*)(H + (size_t)a * 128 + l * 8);
        s0_ += bf_lo(h.x)*w; s1_ += bf_hi(h.x)*w;
        s2_ += bf_lo(h.y)*w; s3_ += bf_hi(h.y)*w;
        s4_ += bf_lo(h.z)*w; s5_ += bf_hi(h.z)*w;
        s6_ += bf_lo(h.w)*w; s7_ += bf_hi(h.w)*w;
    }

    const float self = dn * dn;
    const float4 bA = *(const float4*)&bias[l * 8];
    const float4 bB = *(const float4*)&bias[l * 8 + 4];
    float o0 = fmaxf(s0_ * dn + bf_lo(hq.x) * self + bA.x, 0.0f);
    float o1 = fmaxf(s1_ * dn + bf_hi(hq.x) * self + bA.y, 0.0f);
    float o2 = fmaxf(s2_ * dn + bf_lo(hq.y) * self + bA.z, 0.0f);
    float o3 = fmaxf(s3_ * dn + bf_hi(hq.y) * self + bA.w, 0.0f);
    float o4 = fmaxf(s4_ * dn + bf_lo(hq.z) * self + bB.x, 0.0f);
    float o5 = fmaxf(s5_ * dn + bf_hi(hq.z) * self + bB.y, 0.0f);
    float o6 = fmaxf(s6_ * dn + bf_lo(hq.w) * self + bB.z, 0.0f);
    float o7 = fmaxf(s7_ * dn + bf_hi(hq.w) * self + bB.w, 0.0f);

    if (OUT_BF16) {
        uint4 o;
        o.x = pack2bf(o0, o1); o.y = pack2bf(o2, o3);
        o.z = pack2bf(o4, o5); o.w = pack2bf(o6, o7);
        *(uint4*)((ushort*)OutV + (size_t)node * 128 + l * 8) = o;
    } else {
        float4 oa, ob;
        oa.x = o0; oa.y = o1; oa.z = o2; oa.w = o3;
        ob.x = o4; ob.y = o5; ob.z = o6; ob.w = o7;
        *(float4*)((float*)OutV + (size_t)node * 128 + l * 8)     = oa;
        *(float4*)((float*)OutV + (size_t)node * 128 + l * 8 + 4) = ob;
    }
}

// ---------------------------------------------------------------------------
// Mean pool (sorted batch) + 128x10 linear.
// ---------------------------------------------------------------------------
__global__ __launch_bounds__(128) void pool_kernel(const float* __restrict__ X,
                                                   const int* __restrict__ batch,
                                                   const float* __restrict__ lw,
                                                   const float* __restrict__ lb,
                                                   float* __restrict__ out, int n) {
    const int gph = blockIdx.x;
    int lo = 0, hi = n;
    while (lo < hi) { int mid = (lo + hi) >> 1; if (batch[mid] < gph) lo = mid + 1; else hi = mid; }
    const int s = lo;
    hi = n;
    while (lo < hi) { int mid = (lo + hi) >> 1; if (batch[mid] < gph + 1) lo = mid + 1; else hi = mid; }
    const int e = lo;

    const int t = threadIdx.x;
    float sum = 0.0f;
    for (int i = s; i < e; ++i) sum += X[(size_t)i * 128 + t];
    __shared__ float pl[128];
    pl[t] = sum / fmaxf((float)(e - s), 1.0f);
    __syncthreads();
    if (t < 10) {
        float acc = lb[t];
#pragma unroll 16
        for (int d = 0; d < 128; ++d) acc += pl[d] * lw[d * 10 + t];
        out[gph * 10 + t] = acc;
    }
}

// ---------------------------------------------------------------------------
extern "C" void kernel_launch(void* const* d_in, const int* in_sizes, int n_in,
                              void* d_out, int out_size, void* d_ws, size_t ws_size,
                              hipStream_t stream) {
    const int*   tokens = (const int*)d_in[0];
    const int*   eidx   = (const int*)d_in[1];
    const int*   batch  = (const int*)d_in[2];
    const float* emb    = (const float*)d_in[3];
    const float* w1     = (const float*)d_in[4];
    const float* b1     = (const float*)d_in[5];
    const float* w2     = (const float*)d_in[6];
    const float* b2     = (const float*)d_in[7];
    const float* lw     = (const float*)d_in[8];
    const float* lbv    = (const float*)d_in[9];

    const int N = in_sizes[0];
    const int E = in_sizes[1] / 2;
    const int G = out_size / 10;
    const int* src = eidx;
    const int* dst = eidx + E;
    const int NB = (N + 255) >> 8;          // 256-node buckets (NB <= 256 for N <= 65536)

    char* p = (char*)d_ws;
    auto alloc = [&](size_t bytes) { void* r = (void*)p; p += (bytes + 255) & ~(size_t)255; return r; };
    float*  dis    = (float*)alloc((size_t)N * 4);
    int*    rowptr = (int*)  alloc(((size_t)N + 1) * 4);
    int*    bcnt   = (int*)  alloc(260 * 4);
    int*    boff   = (int*)  alloc(260 * 4);
    int*    bcur   = (int*)  alloc(260 * 4);
    uint*   bstage = (uint*) alloc((size_t)E * 4);
    int*    csr    = (int*)  alloc((size_t)E * 4);
    ushort* A      = (ushort*)alloc((size_t)N * 128 * 2);   // H (bf16)
    ushort* B      = (ushort*)alloc((size_t)N * 128 * 2);   // X2 (bf16)
    float*  C      = (float*) alloc((size_t)N * 128 * 4);   // X3 (f32)

    hipMemsetAsync(bcnt, 0, 260 * 4, stream);

    const int EB = (E + EPB - 1) / EPB;

    bucket_hist   <<<EB, 256, 0, stream>>>(dst, bcnt, E, NB);
    bucket_scan   <<<1, 256, 0, stream>>>(bcnt, boff, bcur, NB);
    bucket_scatter<<<EB, 256, 0, stream>>>(src, dst, bcur, bstage, E, NB);
    csr_build     <<<NB, 256, 0, stream>>>(bstage, boff, dis, rowptr, csr, N, NB, E);

    // layer 1: H = emb[tokens] @ w1 (bf16) ; X2 = relu(agg(H)+b1) (bf16)
    gemm128<<<(N + 63) / 64, 256, 0, stream>>>(nullptr, tokens, emb, w1, A, N);
    aggregate_kernel<true><<<(N + 15) / 16, 256, 0, stream>>>(A, dis, rowptr, csr, b1, B, N);

    // layer 2: H2 = X2 @ w2 (bf16) ; X3 = relu(agg(H2)+b2) (f32)
    gemm128<<<(N + 63) / 64, 256, 0, stream>>>(B, nullptr, nullptr, w2, A, N);
    aggregate_kernel<false><<<(N + 15) / 16, 256, 0, stream>>>(A, dis, rowptr, csr, b2, C, N);

    pool_kernel<<<G, 128, 0, stream>>>(C, batch, lw, lbv, (float*)d_out, N);
}

// Round 6
// 210.156 us; speedup vs baseline: 2.1256x; 1.0846x over previous
//
#include <hip/hip_runtime.h>
#include <hip/hip_bf16.h>

// ---------------------------------------------------------------------------
// GCN classifier.  R1: multi-block scan.  R2: agg unroll x4.  R3: bf16
// activations + 64-row GEMM tiles.  R4: bucketed counting-sort CSR build.
// R5: pool_kernel (43us, latency-bound: 512 blocks serially walking ~98 rows)
//     -> 2-stage segmented reduction (register-accumulated column sums,
//     atomic flush at graph boundaries, then trivial finalize+linear).
//     hipMemsetAsync (43us fillBuffer in graph!) -> init_kernel.
// ---------------------------------------------------------------------------

typedef unsigned int uint;
typedef unsigned short ushort;

__device__ inline float bf_lo(uint u) { return __uint_as_float(u << 16); }
__device__ inline float bf_hi(uint u) { return __uint_as_float(u & 0xffff0000u); }
__device__ inline ushort f2bf(float f) {           // round-to-nearest-even
    uint u = __float_as_uint(f);
    return (ushort)((u + 0x7fffu + ((u >> 16) & 1u)) >> 16);
}
__device__ inline uint pack2bf(float a, float b) {
    return (uint)f2bf(a) | ((uint)f2bf(b) << 16);
}

#define EPB 2048   // edges per block in bucketing kernels

// ---- 0) zero the accumulator region (bcnt | gcnt | pooled) ----------------
__global__ __launch_bounds__(256) void init_kernel(int4* __restrict__ z, int n4) {
    int i = blockIdx.x * blockDim.x + threadIdx.x;
    if (i < n4) z[i] = make_int4(0, 0, 0, 0);
}

// ---- 1) per-bucket histogram (LDS-aggregated) -----------------------------
__global__ __launch_bounds__(256) void bucket_hist(const int* __restrict__ dst,
                                                   int* __restrict__ bcnt, int E, int NB) {
    __shared__ int lh[256];
    const int t = threadIdx.x;
    lh[t] = 0;
    __syncthreads();
    const int base = blockIdx.x * EPB;
    const int end  = min(E, base + EPB);
    for (int i = base + t; i < end; i += 256)
        atomicAdd(&lh[((uint)dst[i]) >> 8], 1);
    __syncthreads();
    if (t < NB && lh[t]) atomicAdd(&bcnt[t], lh[t]);
}

// ---- 2) scan bucket counts -> boff[0..NB]; init bcur ----------------------
__global__ __launch_bounds__(256) void bucket_scan(const int* __restrict__ bcnt,
                                                   int* __restrict__ boff,
                                                   int* __restrict__ bcur, int NB) {
    __shared__ int ls[256];
    const int t = threadIdx.x;
    int v = (t < NB) ? bcnt[t] : 0;
    ls[t] = v;
    __syncthreads();
    for (int off = 1; off < 256; off <<= 1) {
        int x = (t >= off) ? ls[t - off] : 0;
        __syncthreads();
        ls[t] += x;
        __syncthreads();
    }
    int excl = ls[t] - v;
    if (t <= NB) {
        int o = (t < NB) ? excl : ls[255];
        boff[t] = o;
        if (t < NB) bcur[t] = o;
    }
    if (t == 255 && NB < 255) boff[NB] = ls[255];   // ensure boff[NB]=E
}

// ---- 3) scatter edges into bucket-staged array (block-local presort) ------
__global__ __launch_bounds__(256) void bucket_scatter(const int* __restrict__ src,
                                                      const int* __restrict__ dst,
                                                      int* __restrict__ bcur,
                                                      uint* __restrict__ bstage,
                                                      int E, int NB) {
    __shared__ int lh[256];
    __shared__ int lbase[257];
    __shared__ int gbase[256];
    __shared__ int lcur[256];
    __shared__ uint stage[EPB];
    const int t = threadIdx.x;
    const int base = blockIdx.x * EPB;
    const int end  = min(E, base + EPB);
    const int tot  = end - base;

    lh[t] = 0;
    __syncthreads();

    uint pk[8]; int bk[8]; int cnt = 0;
    for (int i = base + t; i < end; i += 256) {
        int s = src[i];
        uint d = (uint)dst[i];
        bk[cnt] = (int)(d >> 8);
        pk[cnt] = (uint)s | ((d & 255u) << 24);
        atomicAdd(&lh[bk[cnt]], 1);
        ++cnt;
    }
    __syncthreads();

    if (t < NB && lh[t]) gbase[t] = atomicAdd(&bcur[t], lh[t]);
    {
        __shared__ int ls[256];
        int v = lh[t];
        ls[t] = v;
        __syncthreads();
        for (int off = 1; off < 256; off <<= 1) {
            int x = (t >= off) ? ls[t - off] : 0;
            __syncthreads();
            ls[t] += x;
            __syncthreads();
        }
        lbase[t] = ls[t] - v;
        if (t == 255) lbase[256] = ls[255];
        lcur[t] = 0;
    }
    __syncthreads();

    for (int j = 0; j < cnt; ++j) {
        int p = lbase[bk[j]] + atomicAdd(&lcur[bk[j]], 1);
        stage[p] = pk[j];
    }
    __syncthreads();

    for (int i = t; i < tot; i += 256) {
        int lo = 0, hi = 256;
        while (lo + 1 < hi) {
            int mid = (lo + hi) >> 1;
            if (lbase[mid] <= i) lo = mid; else hi = mid;
        }
        bstage[gbase[lo] + (i - lbase[lo])] = stage[i];
    }
}

// ---- 4) per-bucket: node hist -> dis + rowptr (coalesced), then CSR -------
__global__ __launch_bounds__(256) void csr_build(const uint* __restrict__ bstage,
                                                 const int* __restrict__ boff,
                                                 float* __restrict__ dis,
                                                 int* __restrict__ rowptr,
                                                 int* __restrict__ csr,
                                                 int N, int NB, int E) {
    __shared__ int lh[256];
    __shared__ int ls[256];
    __shared__ int lbase[256];
    __shared__ int lcur[256];
    const int b = blockIdx.x;
    const int t = threadIdx.x;
    const int base  = boff[b];
    const int cntb  = boff[b + 1] - base;
    const int n0    = b << 8;
    const int nn    = min(256, N - n0);

    lh[t] = 0;
    __syncthreads();
    for (int i = t; i < cntb; i += 256)
        atomicAdd(&lh[bstage[base + i] >> 24], 1);
    __syncthreads();

    const int v = lh[t];
    ls[t] = v;
    __syncthreads();
    for (int off = 1; off < 256; off <<= 1) {
        int x = (t >= off) ? ls[t - off] : 0;
        __syncthreads();
        ls[t] += x;
        __syncthreads();
    }
    lbase[t] = ls[t] - v;
    lcur[t] = 0;
    if (t < nn) {
        dis[n0 + t]    = rsqrtf((float)v + 1.0f);
        rowptr[n0 + t] = base + lbase[t];
    }
    if (b == NB - 1 && t == 0) rowptr[N] = E;
    __syncthreads();

    for (int i = t; i < cntb; i += 256) {
        uint e = bstage[base + i];
        int dl = (int)(e >> 24);
        int pos = base + lbase[dl] + atomicAdd(&lcur[dl], 1);
        csr[pos] = (int)(e & 0xFFFFFFu);
    }
}

// ---------------------------------------------------------------------------
// GEMM: Out_bf16[n,128] = X[n,128] @ W[128,128]
// ---------------------------------------------------------------------------
__global__ __launch_bounds__(256) void gemm128(const ushort* __restrict__ Xbf,
                                               const int* __restrict__ tokens,
                                               const float* __restrict__ emb,
                                               const float* __restrict__ W,
                                               ushort* __restrict__ Out, int n) {
    __shared__ float ws[64 * 128];
    __shared__ float xs[64 * 68];
    const int tid = threadIdx.x;
    const int tc = tid & 15;
    const int tr = tid >> 4;
    const int rowBase = blockIdx.x * 64;

    float acc[4][8];
#pragma unroll
    for (int i = 0; i < 4; ++i)
#pragma unroll
        for (int j = 0; j < 8; ++j) acc[i][j] = 0.0f;

    for (int kk = 0; kk < 128; kk += 64) {
#pragma unroll
        for (int t = 0; t < 8; ++t) {
            int flat4 = t * 256 + tid;
            int r  = flat4 >> 5;
            int c4 = (flat4 & 31) * 4;
            *(float4*)&ws[r * 128 + c4] = *(const float4*)&W[(kk + r) * 128 + c4];
        }
        if (Xbf) {
#pragma unroll
            for (int t = 0; t < 2; ++t) {
                int flat = t * 256 + tid;
                int r  = flat >> 3;
                int c8 = (flat & 7) * 8;
                int grow = rowBase + r;
                float4 a, b;
                if (grow < n) {
                    uint4 q = *(const uint4*)(Xbf + (size_t)grow * 128 + kk + c8);
                    a.x = bf_lo(q.x); a.y = bf_hi(q.x); a.z = bf_lo(q.y); a.w = bf_hi(q.y);
                    b.x = bf_lo(q.z); b.y = bf_hi(q.z); b.z = bf_lo(q.w); b.w = bf_hi(q.w);
                } else {
                    a.x=a.y=a.z=a.w=0.f; b = a;
                }
                *(float4*)&xs[r * 68 + c8]     = a;
                *(float4*)&xs[r * 68 + c8 + 4] = b;
            }
        } else {
#pragma unroll
            for (int t = 0; t < 4; ++t) {
                int flat4 = t * 256 + tid;
                int r  = flat4 >> 4;
                int k4 = (flat4 & 15) * 4;
                int grow = rowBase + r;
                float4 v; v.x = v.y = v.z = v.w = 0.0f;
                if (grow < n) {
                    int tok = tokens[grow];
                    if (tok != 0) v = *(const float4*)&emb[(size_t)tok * 128 + kk + k4];
                }
                *(float4*)&xs[r * 68 + k4] = v;
            }
        }
        __syncthreads();

#pragma unroll
        for (int kc = 0; kc < 16; ++kc) {
            const int k = kc * 4;
            float4 xv[4];
#pragma unroll
            for (int i = 0; i < 4; ++i)
                xv[i] = *(const float4*)&xs[(tr * 4 + i) * 68 + k];
#pragma unroll
            for (int d = 0; d < 4; ++d) {
                float4 wA = *(const float4*)&ws[(k + d) * 128 + tc * 4];
                float4 wB = *(const float4*)&ws[(k + d) * 128 + 64 + tc * 4];
#pragma unroll
                for (int i = 0; i < 4; ++i) {
                    float xd = (d == 0) ? xv[i].x : (d == 1) ? xv[i].y : (d == 2) ? xv[i].z : xv[i].w;
                    acc[i][0] += xd * wA.x;
                    acc[i][1] += xd * wA.y;
                    acc[i][2] += xd * wA.z;
                    acc[i][3] += xd * wA.w;
                    acc[i][4] += xd * wB.x;
                    acc[i][5] += xd * wB.y;
                    acc[i][6] += xd * wB.z;
                    acc[i][7] += xd * wB.w;
                }
            }
        }
        __syncthreads();
    }

#pragma unroll
    for (int i = 0; i < 4; ++i) {
        int r = rowBase + tr * 4 + i;
        if (r < n) {
            uint2 pA, pB;
            pA.x = pack2bf(acc[i][0], acc[i][1]);
            pA.y = pack2bf(acc[i][2], acc[i][3]);
            pB.x = pack2bf(acc[i][4], acc[i][5]);
            pB.y = pack2bf(acc[i][6], acc[i][7]);
            *(uint2*)(Out + (size_t)r * 128 + tc * 4)      = pA;
            *(uint2*)(Out + (size_t)r * 128 + 64 + tc * 4) = pB;
        }
    }
}

// ---------------------------------------------------------------------------
// Aggregation over bf16 H.
// ---------------------------------------------------------------------------
template<bool OUT_BF16>
__global__ __launch_bounds__(256) void aggregate_kernel(const ushort* __restrict__ H,
                                                        const float* __restrict__ dis,
                                                        const int* __restrict__ rowptr,
                                                        const int* __restrict__ csr_src,
                                                        const float* __restrict__ bias,
                                                        void* __restrict__ OutV, int n) {
    const int g = threadIdx.x >> 4;
    const int l = threadIdx.x & 15;
    const int node = blockIdx.x * 16 + g;
    if (node >= n) return;

    const float dn = dis[node];
    const uint4 hq = *(const uint4*)(H + (size_t)node * 128 + l * 8);
    const int e0 = rowptr[node];
    const int e1 = rowptr[node + 1];

    float s0_ = 0.f, s1_ = 0.f, s2_ = 0.f, s3_ = 0.f,
          s4_ = 0.f, s5_ = 0.f, s6_ = 0.f, s7_ = 0.f;

    int e = e0;
    for (; e + 4 <= e1; e += 4) {
        const int a0 = csr_src[e + 0];
        const int a1 = csr_src[e + 1];
        const int a2 = csr_src[e + 2];
        const int a3 = csr_src[e + 3];
        const float w0 = dis[a0];
        const float w1 = dis[a1];
        const float w2 = dis[a2];
        const float w3 = dis[a3];
        const uint4 h0 = *(const uint4*)(H + (size_t)a0 * 128 + l * 8);
        const uint4 h1 = *(const uint4*)(H + (size_t)a1 * 128 + l * 8);
        const uint4 h2 = *(const uint4*)(H + (size_t)a2 * 128 + l * 8);
        const uint4 h3 = *(const uint4*)(H + (size_t)a3 * 128 + l * 8);
        s0_ += bf_lo(h0.x)*w0 + bf_lo(h1.x)*w1 + bf_lo(h2.x)*w2 + bf_lo(h3.x)*w3;
        s1_ += bf_hi(h0.x)*w0 + bf_hi(h1.x)*w1 + bf_hi(h2.x)*w2 + bf_hi(h3.x)*w3;
        s2_ += bf_lo(h0.y)*w0 + bf_lo(h1.y)*w1 + bf_lo(h2.y)*w2 + bf_lo(h3.y)*w3;
        s3_ += bf_hi(h0.y)*w0 + bf_hi(h1.y)*w1 + bf_hi(h2.y)*w2 + bf_hi(h3.y)*w3;
        s4_ += bf_lo(h0.z)*w0 + bf_lo(h1.z)*w1 + bf_lo(h2.z)*w2 + bf_lo(h3.z)*w3;
        s5_ += bf_hi(h0.z)*w0 + bf_hi(h1.z)*w1 + bf_hi(h2.z)*w2 + bf_hi(h3.z)*w3;
        s6_ += bf_lo(h0.w)*w0 + bf_lo(h1.w)*w1 + bf_lo(h2.w)*w2 + bf_lo(h3.w)*w3;
        s7_ += bf_hi(h0.w)*w0 + bf_hi(h1.w)*w1 + bf_hi(h2.w)*w2 + bf_hi(h3.w)*w3;
    }
    for (; e < e1; ++e) {
        const int a = csr_src[e];
        const float w = dis[a];
        const uint4 h = *(const uint4*)(H + (size_t)a * 128 + l * 8);
        s0_ += bf_lo(h.x)*w; s1_ += bf_hi(h.x)*w;
        s2_ += bf_lo(h.y)*w; s3_ += bf_hi(h.y)*w;
        s4_ += bf_lo(h.z)*w; s5_ += bf_hi(h.z)*w;
        s6_ += bf_lo(h.w)*w; s7_ += bf_hi(h.w)*w;
    }

    const float self = dn * dn;
    const float4 bA = *(const float4*)&bias[l * 8];
    const float4 bB = *(const float4*)&bias[l * 8 + 4];
    float o0 = fmaxf(s0_ * dn + bf_lo(hq.x) * self + bA.x, 0.0f);
    float o1 = fmaxf(s1_ * dn + bf_hi(hq.x) * self + bA.y, 0.0f);
    float o2 = fmaxf(s2_ * dn + bf_lo(hq.y) * self + bA.z, 0.0f);
    float o3 = fmaxf(s3_ * dn + bf_hi(hq.y) * self + bA.w, 0.0f);
    float o4 = fmaxf(s4_ * dn + bf_lo(hq.z) * self + bB.x, 0.0f);
    float o5 = fmaxf(s5_ * dn + bf_hi(hq.z) * self + bB.y, 0.0f);
    float o6 = fmaxf(s6_ * dn + bf_lo(hq.w) * self + bB.z, 0.0f);
    float o7 = fmaxf(s7_ * dn + bf_hi(hq.w) * self + bB.w, 0.0f);

    if (OUT_BF16) {
        uint4 o;
        o.x = pack2bf(o0, o1); o.y = pack2bf(o2, o3);
        o.z = pack2bf(o4, o5); o.w = pack2bf(o6, o7);
        *(uint4*)((ushort*)OutV + (size_t)node * 128 + l * 8) = o;
    } else {
        float4 oa, ob;
        oa.x = o0; oa.y = o1; oa.z = o2; oa.w = o3;
        ob.x = o4; ob.y = o5; ob.z = o6; ob.w = o7;
        *(float4*)((float*)OutV + (size_t)node * 128 + l * 8)     = oa;
        *(float4*)((float*)OutV + (size_t)node * 128 + l * 8 + 4) = ob;
    }
}

// ---------------------------------------------------------------------------
// Pool stage 1: segmented column-sum. 256 thr = two 128-thread row-groups,
// each covers 64 rows; register accumulation, atomic flush at graph change.
// ---------------------------------------------------------------------------
__global__ __launch_bounds__(256) void pool_partial(const float* __restrict__ X,
                                                    const int* __restrict__ batch,
                                                    float* __restrict__ pooled,
                                                    int* __restrict__ gcnt, int n) {
    const int grp = threadIdx.x >> 7;
    const int t   = threadIdx.x & 127;
    const int r0  = blockIdx.x * 128 + grp * 64;
    if (r0 >= n) return;
    const int r1 = min(r0 + 64, n);

    int gcur = batch[r0];
    float sum = 0.0f;
    int cnt = 0;
    for (int r = r0; r < r1; ++r) {
        const int g = batch[r];
        const float v = X[(size_t)r * 128 + t];
        if (g != gcur) {
            atomicAdd(&pooled[(size_t)gcur * 128 + t], sum);
            if (t == 0) atomicAdd(&gcnt[gcur], cnt);
            sum = 0.0f; cnt = 0; gcur = g;
        }
        sum += v; ++cnt;
    }
    atomicAdd(&pooled[(size_t)gcur * 128 + t], sum);
    if (t == 0) atomicAdd(&gcnt[gcur], cnt);
}

// ---------------------------------------------------------------------------
// Pool stage 2: divide by count + 128x10 linear.
// ---------------------------------------------------------------------------
__global__ __launch_bounds__(128) void pool_finalize(const float* __restrict__ pooled,
                                                     const int* __restrict__ gcnt,
                                                     const float* __restrict__ lw,
                                                     const float* __restrict__ lb,
                                                     float* __restrict__ out) {
    const int g = blockIdx.x;
    const int t = threadIdx.x;
    __shared__ float pl[128];
    const float c = fmaxf((float)gcnt[g], 1.0f);
    pl[t] = pooled[(size_t)g * 128 + t] / c;
    __syncthreads();
    if (t < 10) {
        float acc = lb[t];
#pragma unroll 16
        for (int d = 0; d < 128; ++d) acc += pl[d] * lw[d * 10 + t];
        out[g * 10 + t] = acc;
    }
}

// ---------------------------------------------------------------------------
extern "C" void kernel_launch(void* const* d_in, const int* in_sizes, int n_in,
                              void* d_out, int out_size, void* d_ws, size_t ws_size,
                              hipStream_t stream) {
    const int*   tokens = (const int*)d_in[0];
    const int*   eidx   = (const int*)d_in[1];
    const int*   batch  = (const int*)d_in[2];
    const float* emb    = (const float*)d_in[3];
    const float* w1     = (const float*)d_in[4];
    const float* b1     = (const float*)d_in[5];
    const float* w2     = (const float*)d_in[6];
    const float* b2     = (const float*)d_in[7];
    const float* lw     = (const float*)d_in[8];
    const float* lbv    = (const float*)d_in[9];

    const int N = in_sizes[0];
    const int E = in_sizes[1] / 2;
    const int G = out_size / 10;
    const int* src = eidx;
    const int* dst = eidx + E;
    const int NB = (N + 255) >> 8;

    char* p = (char*)d_ws;
    auto alloc = [&](size_t bytes) { void* r = (void*)p; p += (bytes + 255) & ~(size_t)255; return r; };
    float*  dis    = (float*)alloc((size_t)N * 4);
    int*    rowptr = (int*)  alloc(((size_t)N + 1) * 4);
    // zeroed-per-call region: bcnt(512) | gcnt(512+pad) | pooled(G*128)
    int*    zreg   = (int*)  alloc((size_t)(1024 + (size_t)G * 128) * 4);
    int*    bcnt   = zreg;                 // 512 ints (NB <= 256, +1 slack)
    int*    gcnt   = zreg + 512;           // G ints (G=512)
    float*  pooled = (float*)(zreg + 1024);
    int*    boff   = (int*)  alloc(260 * 4);
    int*    bcur   = (int*)  alloc(260 * 4);
    uint*   bstage = (uint*) alloc((size_t)E * 4);
    int*    csr    = (int*)  alloc((size_t)E * 4);
    ushort* A      = (ushort*)alloc((size_t)N * 128 * 2);   // H (bf16)
    ushort* B      = (ushort*)alloc((size_t)N * 128 * 2);   // X2 (bf16)
    float*  C      = (float*) alloc((size_t)N * 128 * 4);   // X3 (f32)

    const int ZN4 = (1024 + G * 128) / 4;  // int4 count (divisible by 4)
    const int EB  = (E + EPB - 1) / EPB;

    init_kernel   <<<(ZN4 + 255) / 256, 256, 0, stream>>>((int4*)zreg, ZN4);
    bucket_hist   <<<EB, 256, 0, stream>>>(dst, bcnt, E, NB);
    bucket_scan   <<<1, 256, 0, stream>>>(bcnt, boff, bcur, NB);
    bucket_scatter<<<EB, 256, 0, stream>>>(src, dst, bcur, bstage, E, NB);
    csr_build     <<<NB, 256, 0, stream>>>(bstage, boff, dis, rowptr, csr, N, NB, E);

    // layer 1: H = emb[tokens] @ w1 (bf16) ; X2 = relu(agg(H)+b1) (bf16)
    gemm128<<<(N + 63) / 64, 256, 0, stream>>>(nullptr, tokens, emb, w1, A, N);
    aggregate_kernel<true><<<(N + 15) / 16, 256, 0, stream>>>(A, dis, rowptr, csr, b1, B, N);

    // layer 2: H2 = X2 @ w2 (bf16) ; X3 = relu(agg(H2)+b2) (f32)
    gemm128<<<(N + 63) / 64, 256, 0, stream>>>(B, nullptr, nullptr, w2, A, N);
    aggregate_kernel<false><<<(N + 15) / 16, 256, 0, stream>>>(A, dis, rowptr, csr, b2, C, N);

    // mean pool + classifier
    pool_partial <<<(N + 127) / 128, 256, 0, stream>>>(C, batch, pooled, gcnt, N);
    pool_finalize<<<G, 128, 0, stream>>>(pooled, gcnt, lw, lbv, (float*)d_out);
}

// Round 7
// 166.729 us; speedup vs baseline: 2.6792x; 1.2605x over previous
//
#include <hip/hip_runtime.h>
#include <hip/hip_bf16.h>

// ---------------------------------------------------------------------------
// GCN classifier.  R1: multi-block scan.  R2: agg unroll x4.  R3: bf16
// activations + 64-row GEMM tiles.  R4: bucketed counting-sort CSR build.
// R5: 2-stage pool + init kernel (memset removed from graph).
// R6: MFMA GEMM (v_mfma_f32_16x16x32_bf16): weights pre-transposed+bf16
//     (Wt[n][k]), staged in LDS with XOR swizzle; A-frags straight from
//     global (emb-gather fused for layer 1). Old VALU gemm was 42us at 36%
//     VALUBusy; MFMA math is ~1us, kernel becomes L2/HBM-bound.
// ---------------------------------------------------------------------------

typedef unsigned int uint;
typedef unsigned short ushort;
typedef __attribute__((ext_vector_type(8))) short bf16x8;
typedef __attribute__((ext_vector_type(4))) float f32x4;

__device__ inline float bf_lo(uint u) { return __uint_as_float(u << 16); }
__device__ inline float bf_hi(uint u) { return __uint_as_float(u & 0xffff0000u); }
__device__ inline ushort f2bf(float f) {           // round-to-nearest-even
    uint u = __float_as_uint(f);
    return (ushort)((u + 0x7fffu + ((u >> 16) & 1u)) >> 16);
}
__device__ inline uint pack2bf(float a, float b) {
    return (uint)f2bf(a) | ((uint)f2bf(b) << 16);
}

#define EPB 2048   // edges per block in bucketing kernels

// ---- 0) zero the accumulator region (bcnt | gcnt | pooled) ----------------
__global__ __launch_bounds__(256) void init_kernel(int4* __restrict__ z, int n4) {
    int i = blockIdx.x * blockDim.x + threadIdx.x;
    if (i < n4) z[i] = make_int4(0, 0, 0, 0);
}

// ---- 0b) weight convert: W[k][n] f32 -> Wt[n][k] bf16 ---------------------
__global__ __launch_bounds__(256) void convert_w(const float* __restrict__ Win,
                                                 ushort* __restrict__ Wt) {
    int i = blockIdx.x * 256 + threadIdx.x;      // 0..16383
    int nn = i >> 7, k = i & 127;
    Wt[i] = f2bf(Win[k * 128 + nn]);
}

// ---- 1) per-bucket histogram (LDS-aggregated) -----------------------------
__global__ __launch_bounds__(256) void bucket_hist(const int* __restrict__ dst,
                                                   int* __restrict__ bcnt, int E, int NB) {
    __shared__ int lh[256];
    const int t = threadIdx.x;
    lh[t] = 0;
    __syncthreads();
    const int base = blockIdx.x * EPB;
    const int end  = min(E, base + EPB);
    for (int i = base + t; i < end; i += 256)
        atomicAdd(&lh[((uint)dst[i]) >> 8], 1);
    __syncthreads();
    if (t < NB && lh[t]) atomicAdd(&bcnt[t], lh[t]);
}

// ---- 2) scan bucket counts -> boff[0..NB]; init bcur ----------------------
__global__ __launch_bounds__(256) void bucket_scan(const int* __restrict__ bcnt,
                                                   int* __restrict__ boff,
                                                   int* __restrict__ bcur, int NB) {
    __shared__ int ls[256];
    const int t = threadIdx.x;
    int v = (t < NB) ? bcnt[t] : 0;
    ls[t] = v;
    __syncthreads();
    for (int off = 1; off < 256; off <<= 1) {
        int x = (t >= off) ? ls[t - off] : 0;
        __syncthreads();
        ls[t] += x;
        __syncthreads();
    }
    int excl = ls[t] - v;
    if (t <= NB) {
        int o = (t < NB) ? excl : ls[255];
        boff[t] = o;
        if (t < NB) bcur[t] = o;
    }
    if (t == 255 && NB < 255) boff[NB] = ls[255];
}

// ---- 3) scatter edges into bucket-staged array (block-local presort) ------
__global__ __launch_bounds__(256) void bucket_scatter(const int* __restrict__ src,
                                                      const int* __restrict__ dst,
                                                      int* __restrict__ bcur,
                                                      uint* __restrict__ bstage,
                                                      int E, int NB) {
    __shared__ int lh[256];
    __shared__ int lbase[257];
    __shared__ int gbase[256];
    __shared__ int lcur[256];
    __shared__ uint stage[EPB];
    const int t = threadIdx.x;
    const int base = blockIdx.x * EPB;
    const int end  = min(E, base + EPB);
    const int tot  = end - base;

    lh[t] = 0;
    __syncthreads();

    uint pk[8]; int bk[8]; int cnt = 0;
    for (int i = base + t; i < end; i += 256) {
        int s = src[i];
        uint d = (uint)dst[i];
        bk[cnt] = (int)(d >> 8);
        pk[cnt] = (uint)s | ((d & 255u) << 24);
        atomicAdd(&lh[bk[cnt]], 1);
        ++cnt;
    }
    __syncthreads();

    if (t < NB && lh[t]) gbase[t] = atomicAdd(&bcur[t], lh[t]);
    {
        __shared__ int ls[256];
        int v = lh[t];
        ls[t] = v;
        __syncthreads();
        for (int off = 1; off < 256; off <<= 1) {
            int x = (t >= off) ? ls[t - off] : 0;
            __syncthreads();
            ls[t] += x;
            __syncthreads();
        }
        lbase[t] = ls[t] - v;
        if (t == 255) lbase[256] = ls[255];
        lcur[t] = 0;
    }
    __syncthreads();

    for (int j = 0; j < cnt; ++j) {
        int p = lbase[bk[j]] + atomicAdd(&lcur[bk[j]], 1);
        stage[p] = pk[j];
    }
    __syncthreads();

    for (int i = t; i < tot; i += 256) {
        int lo = 0, hi = 256;
        while (lo + 1 < hi) {
            int mid = (lo + hi) >> 1;
            if (lbase[mid] <= i) lo = mid; else hi = mid;
        }
        bstage[gbase[lo] + (i - lbase[lo])] = stage[i];
    }
}

// ---- 4) per-bucket: node hist -> dis + rowptr (coalesced), then CSR -------
__global__ __launch_bounds__(256) void csr_build(const uint* __restrict__ bstage,
                                                 const int* __restrict__ boff,
                                                 float* __restrict__ dis,
                                                 int* __restrict__ rowptr,
                                                 int* __restrict__ csr,
                                                 int N, int NB, int E) {
    __shared__ int lh[256];
    __shared__ int ls[256];
    __shared__ int lbase[256];
    __shared__ int lcur[256];
    const int b = blockIdx.x;
    const int t = threadIdx.x;
    const int base  = boff[b];
    const int cntb  = boff[b + 1] - base;
    const int n0    = b << 8;
    const int nn    = min(256, N - n0);

    lh[t] = 0;
    __syncthreads();
    for (int i = t; i < cntb; i += 256)
        atomicAdd(&lh[bstage[base + i] >> 24], 1);
    __syncthreads();

    const int v = lh[t];
    ls[t] = v;
    __syncthreads();
    for (int off = 1; off < 256; off <<= 1) {
        int x = (t >= off) ? ls[t - off] : 0;
        __syncthreads();
        ls[t] += x;
        __syncthreads();
    }
    lbase[t] = ls[t] - v;
    lcur[t] = 0;
    if (t < nn) {
        dis[n0 + t]    = rsqrtf((float)v + 1.0f);
        rowptr[n0 + t] = base + lbase[t];
    }
    if (b == NB - 1 && t == 0) rowptr[N] = E;
    __syncthreads();

    for (int i = t; i < cntb; i += 256) {
        uint e = bstage[base + i];
        int dl = (int)(e >> 24);
        int pos = base + lbase[dl] + atomicAdd(&lcur[dl], 1);
        csr[pos] = (int)(e & 0xFFFFFFu);
    }
}

// ---------------------------------------------------------------------------
// MFMA GEMM: Out_bf16[n,128] = A[n,128] @ W[128,128]
// Wt: bf16, pre-transposed [n(out col)][k].  A: bf16 rows (or emb-gather if
// GATHER).  Block = 256 thr = 4 waves, 128 rows/block, wave = 32 rows.
// LDS: Wt swizzled (byte ^= (row&7)<<4), ds_read_b128 conflict-free (2/bank).
// Frag layouts (16x16x32): A/B lane l -> (m|n = l&15, k = (l>>4)*8+j);
// C/D lane l, reg r -> (col = l&15, row = (l>>4)*4 + r).
// ---------------------------------------------------------------------------
template<bool GATHER>
__global__ __launch_bounds__(256) void gemm_mfma(const ushort* __restrict__ Xbf,
                                                 const int* __restrict__ tokens,
                                                 const float* __restrict__ emb,
                                                 const ushort* __restrict__ Wt,
                                                 ushort* __restrict__ Out, int n) {
    __shared__ ushort wl[128 * 128];   // 32KB, swizzled
    const int tid = threadIdx.x;

    // stage Wt -> LDS (coalesced global uint4, swizzled b128 writes)
    {
        const int row  = tid >> 1;            // 0..127 (output col n)
        const int half = tid & 1;
        const int base = row * 256 + half * 128;   // byte offset in Wt
#pragma unroll
        for (int i = 0; i < 8; ++i) {
            int off = base + i * 16;
            uint4 v = *(const uint4*)((const char*)Wt + off);
            int swz = off ^ ((row & 7) << 4);
            *(uint4*)((char*)wl + swz) = v;
        }
    }
    __syncthreads();

    const int w  = tid >> 6;          // wave 0..3
    const int l  = tid & 63;
    const int lr = l & 15;
    const int lg = l >> 4;            // 0..3
    const int rowBase = blockIdx.x * 128 + w * 32;

    f32x4 acc[2][8];
#pragma unroll
    for (int s = 0; s < 2; ++s)
#pragma unroll
        for (int ct = 0; ct < 8; ++ct) acc[s][ct] = (f32x4){0.f, 0.f, 0.f, 0.f};

    // A fragments: strip s covers rows rowBase + s*16 + (l&15)
    bf16x8 afrag[2][4];
#pragma unroll
    for (int s = 0; s < 2; ++s) {
        const int row = rowBase + s * 16 + lr;
        if (row < n) {
            if (GATHER) {
                const int tok = tokens[row];
                if (tok != 0) {
                    const float* ep = emb + (size_t)tok * 128;
#pragma unroll
                    for (int kk = 0; kk < 4; ++kk) {
                        const float* q = ep + kk * 32 + lg * 8;
                        float4 lo = *(const float4*)q;
                        float4 hi = *(const float4*)(q + 4);
                        uint4 pk;
                        pk.x = pack2bf(lo.x, lo.y); pk.y = pack2bf(lo.z, lo.w);
                        pk.z = pack2bf(hi.x, hi.y); pk.w = pack2bf(hi.z, hi.w);
                        union { uint4 u; bf16x8 b; } c; c.u = pk;
                        afrag[s][kk] = c.b;
                    }
                } else {
#pragma unroll
                    for (int kk = 0; kk < 4; ++kk) afrag[s][kk] = (bf16x8){0,0,0,0,0,0,0,0};
                }
            } else {
                const ushort* xp = Xbf + (size_t)row * 128;
#pragma unroll
                for (int kk = 0; kk < 4; ++kk)
                    afrag[s][kk] = *(const bf16x8*)(xp + kk * 32 + lg * 8);
            }
        } else {
#pragma unroll
            for (int kk = 0; kk < 4; ++kk) afrag[s][kk] = (bf16x8){0,0,0,0,0,0,0,0};
        }
    }

    // MFMA main: 8 col tiles x 4 k-chunks x 2 strips
#pragma unroll
    for (int ct = 0; ct < 8; ++ct) {
#pragma unroll
        for (int kk = 0; kk < 4; ++kk) {
            const int nrow = ct * 16 + lr;
            int off = nrow * 256 + kk * 64 + lg * 16;
            off ^= ((nrow & 7) << 4);
            bf16x8 b = *(const bf16x8*)((const char*)wl + off);
            acc[0][ct] = __builtin_amdgcn_mfma_f32_16x16x32_bf16(afrag[0][kk], b, acc[0][ct], 0, 0, 0);
            acc[1][ct] = __builtin_amdgcn_mfma_f32_16x16x32_bf16(afrag[1][kk], b, acc[1][ct], 0, 0, 0);
        }
    }

    // store C (bf16): lane l, reg r -> row = base + s*16 + lg*4 + r, col = ct*16 + lr
#pragma unroll
    for (int s = 0; s < 2; ++s) {
#pragma unroll
        for (int r = 0; r < 4; ++r) {
            const int row = rowBase + s * 16 + lg * 4 + r;
            if (row < n) {
                ushort* op = Out + (size_t)row * 128 + lr;
#pragma unroll
                for (int ct = 0; ct < 8; ++ct)
                    op[ct * 16] = f2bf(acc[s][ct][r]);
            }
        }
    }
}

// ---------------------------------------------------------------------------
// Aggregation over bf16 H.
// ---------------------------------------------------------------------------
template<bool OUT_BF16>
__global__ __launch_bounds__(256) void aggregate_kernel(const ushort* __restrict__ H,
                                                        const float* __restrict__ dis,
                                                        const int* __restrict__ rowptr,
                                                        const int* __restrict__ csr_src,
                                                        const float* __restrict__ bias,
                                                        void* __restrict__ OutV, int n) {
    const int g = threadIdx.x >> 4;
    const int l = threadIdx.x & 15;
    const int node = blockIdx.x * 16 + g;
    if (node >= n) return;

    const float dn = dis[node];
    const uint4 hq = *(const uint4*)(H + (size_t)node * 128 + l * 8);
    const int e0 = rowptr[node];
    const int e1 = rowptr[node + 1];

    float s0_ = 0.f, s1_ = 0.f, s2_ = 0.f, s3_ = 0.f,
          s4_ = 0.f, s5_ = 0.f, s6_ = 0.f, s7_ = 0.f;

    int e = e0;
    for (; e + 4 <= e1; e += 4) {
        const int a0 = csr_src[e + 0];
        const int a1 = csr_src[e + 1];
        const int a2 = csr_src[e + 2];
        const int a3 = csr_src[e + 3];
        const float w0 = dis[a0];
        const float w1 = dis[a1];
        const float w2 = dis[a2];
        const float w3 = dis[a3];
        const uint4 h0 = *(const uint4*)(H + (size_t)a0 * 128 + l * 8);
        const uint4 h1 = *(const uint4*)(H + (size_t)a1 * 128 + l * 8);
        const uint4 h2 = *(const uint4*)(H + (size_t)a2 * 128 + l * 8);
        const uint4 h3 = *(const uint4*)(H + (size_t)a3 * 128 + l * 8);
        s0_ += bf_lo(h0.x)*w0 + bf_lo(h1.x)*w1 + bf_lo(h2.x)*w2 + bf_lo(h3.x)*w3;
        s1_ += bf_hi(h0.x)*w0 + bf_hi(h1.x)*w1 + bf_hi(h2.x)*w2 + bf_hi(h3.x)*w3;
        s2_ += bf_lo(h0.y)*w0 + bf_lo(h1.y)*w1 + bf_lo(h2.y)*w2 + bf_lo(h3.y)*w3;
        s3_ += bf_hi(h0.y)*w0 + bf_hi(h1.y)*w1 + bf_hi(h2.y)*w2 + bf_hi(h3.y)*w3;
        s4_ += bf_lo(h0.z)*w0 + bf_lo(h1.z)*w1 + bf_lo(h2.z)*w2 + bf_lo(h3.z)*w3;
        s5_ += bf_hi(h0.z)*w0 + bf_hi(h1.z)*w1 + bf_hi(h2.z)*w2 + bf_hi(h3.z)*w3;
        s6_ += bf_lo(h0.w)*w0 + bf_lo(h1.w)*w1 + bf_lo(h2.w)*w2 + bf_lo(h3.w)*w3;
        s7_ += bf_hi(h0.w)*w0 + bf_hi(h1.w)*w1 + bf_hi(h2.w)*w2 + bf_hi(h3.w)*w3;
    }
    for (; e < e1; ++e) {
        const int a = csr_src[e];
        const float w = dis[a];
        const uint4 h = *(const uint4*)(H + (size_t)a * 128 + l * 8);
        s0_ += bf_lo(h.x)*w; s1_ += bf_hi(h.x)*w;
        s2_ += bf_lo(h.y)*w; s3_ += bf_hi(h.y)*w;
        s4_ += bf_lo(h.z)*w; s5_ += bf_hi(h.z)*w;
        s6_ += bf_lo(h.w)*w; s7_ += bf_hi(h.w)*w;
    }

    const float self = dn * dn;
    const float4 bA = *(const float4*)&bias[l * 8];
    const float4 bB = *(const float4*)&bias[l * 8 + 4];
    float o0 = fmaxf(s0_ * dn + bf_lo(hq.x) * self + bA.x, 0.0f);
    float o1 = fmaxf(s1_ * dn + bf_hi(hq.x) * self + bA.y, 0.0f);
    float o2 = fmaxf(s2_ * dn + bf_lo(hq.y) * self + bA.z, 0.0f);
    float o3 = fmaxf(s3_ * dn + bf_hi(hq.y) * self + bA.w, 0.0f);
    float o4 = fmaxf(s4_ * dn + bf_lo(hq.z) * self + bB.x, 0.0f);
    float o5 = fmaxf(s5_ * dn + bf_hi(hq.z) * self + bB.y, 0.0f);
    float o6 = fmaxf(s6_ * dn + bf_lo(hq.w) * self + bB.z, 0.0f);
    float o7 = fmaxf(s7_ * dn + bf_hi(hq.w) * self + bB.w, 0.0f);

    if (OUT_BF16) {
        uint4 o;
        o.x = pack2bf(o0, o1); o.y = pack2bf(o2, o3);
        o.z = pack2bf(o4, o5); o.w = pack2bf(o6, o7);
        *(uint4*)((ushort*)OutV + (size_t)node * 128 + l * 8) = o;
    } else {
        float4 oa, ob;
        oa.x = o0; oa.y = o1; oa.z = o2; oa.w = o3;
        ob.x = o4; ob.y = o5; ob.z = o6; ob.w = o7;
        *(float4*)((float*)OutV + (size_t)node * 128 + l * 8)     = oa;
        *(float4*)((float*)OutV + (size_t)node * 128 + l * 8 + 4) = ob;
    }
}

// ---------------------------------------------------------------------------
// Pool stage 1: segmented column-sum (register accumulate, flush per segment)
// ---------------------------------------------------------------------------
__global__ __launch_bounds__(256) void pool_partial(const float* __restrict__ X,
                                                    const int* __restrict__ batch,
                                                    float* __restrict__ pooled,
                                                    int* __restrict__ gcnt, int n) {
    const int grp = threadIdx.x >> 7;
    const int t   = threadIdx.x & 127;
    const int r0  = blockIdx.x * 128 + grp * 64;
    if (r0 >= n) return;
    const int r1 = min(r0 + 64, n);

    int gcur = batch[r0];
    float sum = 0.0f;
    int cnt = 0;
    for (int r = r0; r < r1; ++r) {
        const int g = batch[r];
        const float v = X[(size_t)r * 128 + t];
        if (g != gcur) {
            atomicAdd(&pooled[(size_t)gcur * 128 + t], sum);
            if (t == 0) atomicAdd(&gcnt[gcur], cnt);
            sum = 0.0f; cnt = 0; gcur = g;
        }
        sum += v; ++cnt;
    }
    atomicAdd(&pooled[(size_t)gcur * 128 + t], sum);
    if (t == 0) atomicAdd(&gcnt[gcur], cnt);
}

// ---------------------------------------------------------------------------
// Pool stage 2: divide by count + 128x10 linear.
// ---------------------------------------------------------------------------
__global__ __launch_bounds__(128) void pool_finalize(const float* __restrict__ pooled,
                                                     const int* __restrict__ gcnt,
                                                     const float* __restrict__ lw,
                                                     const float* __restrict__ lb,
                                                     float* __restrict__ out) {
    const int g = blockIdx.x;
    const int t = threadIdx.x;
    __shared__ float pl[128];
    const float c = fmaxf((float)gcnt[g], 1.0f);
    pl[t] = pooled[(size_t)g * 128 + t] / c;
    __syncthreads();
    if (t < 10) {
        float acc = lb[t];
#pragma unroll 16
        for (int d = 0; d < 128; ++d) acc += pl[d] * lw[d * 10 + t];
        out[g * 10 + t] = acc;
    }
}

// ---------------------------------------------------------------------------
extern "C" void kernel_launch(void* const* d_in, const int* in_sizes, int n_in,
                              void* d_out, int out_size, void* d_ws, size_t ws_size,
                              hipStream_t stream) {
    const int*   tokens = (const int*)d_in[0];
    const int*   eidx   = (const int*)d_in[1];
    const int*   batch  = (const int*)d_in[2];
    const float* emb    = (const float*)d_in[3];
    const float* w1     = (const float*)d_in[4];
    const float* b1     = (const float*)d_in[5];
    const float* w2     = (const float*)d_in[6];
    const float* b2     = (const float*)d_in[7];
    const float* lw     = (const float*)d_in[8];
    const float* lbv    = (const float*)d_in[9];

    const int N = in_sizes[0];
    const int E = in_sizes[1] / 2;
    const int G = out_size / 10;
    const int* src = eidx;
    const int* dst = eidx + E;
    const int NB = (N + 255) >> 8;

    char* p = (char*)d_ws;
    auto alloc = [&](size_t bytes) { void* r = (void*)p; p += (bytes + 255) & ~(size_t)255; return r; };
    float*  dis    = (float*)alloc((size_t)N * 4);
    int*    rowptr = (int*)  alloc(((size_t)N + 1) * 4);
    int*    zreg   = (int*)  alloc((size_t)(1024 + (size_t)G * 128) * 4);
    int*    bcnt   = zreg;
    int*    gcnt   = zreg + 512;
    float*  pooled = (float*)(zreg + 1024);
    int*    boff   = (int*)  alloc(260 * 4);
    int*    bcur   = (int*)  alloc(260 * 4);
    uint*   bstage = (uint*) alloc((size_t)E * 4);
    int*    csr    = (int*)  alloc((size_t)E * 4);
    ushort* W1t    = (ushort*)alloc(16384 * 2);
    ushort* W2t    = (ushort*)alloc(16384 * 2);
    ushort* A      = (ushort*)alloc((size_t)N * 128 * 2);   // H (bf16)
    ushort* B      = (ushort*)alloc((size_t)N * 128 * 2);   // X2 (bf16)
    float*  C      = (float*) alloc((size_t)N * 128 * 4);   // X3 (f32)

    const int ZN4 = (1024 + G * 128) / 4;
    const int EB  = (E + EPB - 1) / EPB;

    init_kernel   <<<(ZN4 + 255) / 256, 256, 0, stream>>>((int4*)zreg, ZN4);
    convert_w     <<<64, 256, 0, stream>>>(w1, W1t);
    convert_w     <<<64, 256, 0, stream>>>(w2, W2t);
    bucket_hist   <<<EB, 256, 0, stream>>>(dst, bcnt, E, NB);
    bucket_scan   <<<1, 256, 0, stream>>>(bcnt, boff, bcur, NB);
    bucket_scatter<<<EB, 256, 0, stream>>>(src, dst, bcur, bstage, E, NB);
    csr_build     <<<NB, 256, 0, stream>>>(bstage, boff, dis, rowptr, csr, N, NB, E);

    // layer 1: H = bf16(emb[tokens]) @ W1 ; X2 = relu(agg(H)+b1) (bf16)
    gemm_mfma<true><<<(N + 127) / 128, 256, 0, stream>>>(nullptr, tokens, emb, W1t, A, N);
    aggregate_kernel<true><<<(N + 15) / 16, 256, 0, stream>>>(A, dis, rowptr, csr, b1, B, N);

    // layer 2: H2 = X2 @ W2 ; X3 = relu(agg(H2)+b2) (f32)
    gemm_mfma<false><<<(N + 127) / 128, 256, 0, stream>>>(B, nullptr, nullptr, W2t, A, N);
    aggregate_kernel<false><<<(N + 15) / 16, 256, 0, stream>>>(A, dis, rowptr, csr, b2, C, N);

    // mean pool + classifier
    pool_partial <<<(N + 127) / 128, 256, 0, stream>>>(C, batch, pooled, gcnt, N);
    pool_finalize<<<G, 128, 0, stream>>>(pooled, gcnt, lw, lbv, (float*)d_out);
}